// Round 13
// baseline (479.706 us; speedup 1.0000x reference)
//
#include <hip/hip_runtime.h>
#include <hip/hip_fp16.h>

#define LDIM 512
#define BDIM 16

// ws layout: small arrays first so the fallback path works with small ws.
#define WS_A    0u          // 262144 B  (float EA[256*256], EA[x*256+q] = exp(A))
#define WS_CE   262144u     // 1024 B
#define WS_LOM  263168u     // 1024 B
#define WS_LAL  264192u     // 1024 B
#define WS_PS   265216u     // 64 B
#define WS_W    270336u     // 16777216 B (fp8 W, MFMA fragment layout), 16B aligned
#define WS_FAST_BYTES (270336ull + 16777216ull)

typedef float f32x4 __attribute__((ext_vector_type(4)));
typedef int   i32x8 __attribute__((ext_vector_type(8)));
typedef unsigned int u32x4 __attribute__((ext_vector_type(4)));

__device__ __forceinline__ float wred_add(float v) {
    #pragma unroll
    for (int off = 32; off; off >>= 1) v += __shfl_xor(v, off);
    return v;
}
__device__ __forceinline__ float wred_max(float v) {
    #pragma unroll
    for (int off = 32; off; off >>= 1) v = fmaxf(v, __shfl_xor(v, off));
    return v;
}

#if __has_builtin(__builtin_amdgcn_cvt_pk_f32_fp8) && __has_builtin(__builtin_amdgcn_cvt_pk_fp8_f32)
#define HW_FP8 1
#else
#define HW_FP8 0
#endif
#if __has_builtin(__builtin_amdgcn_mfma_scale_f32_16x16x128_f8f6f4)
#define HW_MXF8 1
#else
#define HW_MXF8 0
#endif

// Fallback software e4m3fn (normals only).
__device__ __forceinline__ unsigned int sw_fp8_enc(float a) {
    union { float f; unsigned int u; } x; x.f = a;
    unsigned int u = x.u + 0x80000u;               // round at mantissa bit 19
    return (((u >> 23) & 0xffu) - 120u) * 8u + ((u >> 20) & 7u);
}
__device__ __forceinline__ unsigned int pack4_fp8(float a, float b, float c, float d) {
#if HW_FP8
    int v = 0;
    v = __builtin_amdgcn_cvt_pk_fp8_f32(a, b, v, false);   // bytes 0,1
    v = __builtin_amdgcn_cvt_pk_fp8_f32(c, d, v, true);    // bytes 2,3
    return (unsigned int)v;
#else
    return sw_fp8_enc(a) | (sw_fp8_enc(b) << 8) | (sw_fp8_enc(c) << 16) | (sw_fp8_enc(d) << 24);
#endif
}
__device__ __forceinline__ unsigned char fp8_1(float a) {
#if HW_FP8
    return (unsigned char)(__builtin_amdgcn_cvt_pk_fp8_f32(a, a, 0, false) & 0xff);
#else
    return (unsigned char)sw_fp8_enc(a);
#endif
}

__device__ __forceinline__ long mk64(unsigned int lo, unsigned int hi) {
    return (long)(((unsigned long long)hi << 32) | (unsigned long long)lo);
}
__device__ __forceinline__ i32x8 pk8(u32x4 a, u32x4 b) {
    i32x8 r;
    r[0] = (int)a[0]; r[1] = (int)a[1]; r[2] = (int)a[2]; r[3] = (int)a[3];
    r[4] = (int)b[0]; r[5] = (int)b[1]; r[6] = (int)b[2]; r[7] = (int)b[3];
    return r;
}

// Raw barrier: only drains LDS (lgkmcnt). Global prefetch loads stay in
// flight across it. sched_barrier(0) fences pin compile-time ordering.
__device__ __forceinline__ void sync_lds() {
    asm volatile("s_waitcnt lgkmcnt(0)" ::: "memory");
    __builtin_amdgcn_sched_barrier(0);
    __builtin_amdgcn_s_barrier();
    __builtin_amdgcn_sched_barrier(0);
    asm volatile("" ::: "memory");
}

// Michelot exact sparsemax over a wave's 256 values (4 per lane).
// Returns c = <z,p*> - 0.5||p*||^2 + 0.5 (wave-uniform).
__device__ float sparsemax_c4(float z0, float z1, float z2, float z3) {
    float ssum = wred_add(z0 + z1 + z2 + z3);
    float tau = (ssum - 1.0f) * (1.0f / 256.0f);
    int kprev = 256;
    for (int it = 0; it < 64; ++it) {
        float s = 0.f, cnt = 0.f;
        if (z0 > tau) { s += z0; cnt += 1.f; }
        if (z1 > tau) { s += z1; cnt += 1.f; }
        if (z2 > tau) { s += z2; cnt += 1.f; }
        if (z3 > tau) { s += z3; cnt += 1.f; }
        s = wred_add(s);
        cnt = wred_add(cnt);
        tau = (s - 1.0f) / cnt;            // cnt >= 1 invariant (max > tau)
        int k = (int)cnt;
        if (k == kprev) break;
        kprev = k;
    }
    float cs = 0.f, t2 = tau * tau;
    if (z0 > tau) cs += z0 * z0 - t2;
    if (z1 > tau) cs += z1 * z1 - t2;
    if (z2 > tau) cs += z2 * z2 - t2;
    if (z3 > tau) cs += z3 * z3 - t2;
    cs = wred_add(cs);
    return 0.5f * cs + 0.5f;
}

// Rows of E (256) + omega (1) + alpha (1). All float32.
__global__ __launch_bounds__(256) void k_erow(const float* E, const float* omega,
                                              const float* alpha,
                                              float* cE, float* LOm, float* LAl) {
    int wid = blockIdx.x * 4 + (threadIdx.x >> 6);
    if (wid >= 258) return;
    int lane = threadIdx.x & 63;
    const float* row = (wid < 256) ? (E + wid * 256)
                      : (wid == 256 ? omega : alpha);
    float4 z = *(const float4*)(row + lane * 4);
    float c = sparsemax_c4(z.x, z.y, z.z, z.w);
    if (wid < 256) {
        if (lane == 0) cE[wid] = c;
    } else {
        float* dst = (wid == 256) ? LOm : LAl;
        *(float4*)(dst + lane * 4) = make_float4(c - z.x, c - z.y, c - z.z, c - z.w);
    }
}

// wid = x*256+q.  Fused: EA[x*256+q] = exp(c_T(T[q,x,:]) + cE[q] - E[q,x]).
// W8 in MFMA fp8 A-fragment order (round-5-verified for the scaled
// 16x16x128 fp8/fp8 contraction — the per-(group,dword,byte) k-map of A
// equals the k-map of the u8b B-fragments):
//   main-kernel wave w (q-tile 16w..16w+15), lane l, uint4 #i2 reads 16 B at
//     x*65536 + w*4096 + i2*1024 + l*16
//   low 8 B = chunk c=2*i2  (k = 32c + 8*(l>>4) + j, j=0..7), high 8 B = 2*i2+1.
// NOTE (round-8 lesson): do NOT port W to fp6/fp4 — the f8f6f4 sub-byte
// register bit-layout is undocumented and a wrong guess is silent garbage.
// NOTE (round-11 lesson): do NOT deepen the register prefetch ring past 2 —
// SIInsertWaitcnts can't see into inline asm, and at ~128-VGPR pressure the
// allocator copies/spills in-flight asm-load destinations (silent stale data).
// R10: block's 16 waves scatter into a 4-KB LDS buffer, then 256 threads
// store contiguous uint4 (measured neutral vs direct scatter; kept).
__global__ __launch_bounds__(1024) void k_trow(const float* T, const float* E,
                                               const float* cE, unsigned char* W8,
                                               float* EA, int writeW) {
    int tid = threadIdx.x;
    int wid = blockIdx.x * 16 + (tid >> 6);
    int lane = tid & 63;
    int x = wid >> 8, q = wid & 255;
    __shared__ __align__(16) unsigned int wbuf[1024];
    const float* row = T + ((size_t)((q << 8) | x) << 8);
    float4 z = *(const float4*)(row + lane * 4);
    float c = sparsemax_c4(z.x, z.y, z.z, z.w);
    if (writeW) {                              // block-uniform
        unsigned int packed = pack4_fp8(__expf(-z.x), __expf(-z.y),
                                        __expf(-z.z), __expf(-z.w));
        int n0 = lane << 2;                // 4 consecutive n share i2,g,half
        // intra-4KB dword index: i2<<8 | g<<6 | (q&15)<<2 | half<<1 | j0>>2
        int lidx = ((n0 >> 6) << 8) | (((n0 >> 3) & 3) << 6)
                 | ((q & 15) << 2) | (((n0 >> 5) & 1) << 1) | ((n0 & 7) >> 2);
        wbuf[lidx] = packed;
        __syncthreads();
        if (tid < 256) {
            size_t base = ((size_t)x << 16) + ((size_t)(q >> 4) << 12);
            *(uint4*)(W8 + base + ((size_t)tid << 4)) =
                *(const uint4*)((const unsigned char*)wbuf + (tid << 4));
        }
    }
    if (lane == 0) EA[wid] = __expf(c + cE[q] - E[(q << 8) + x]);
}

// Prefetch one step's W (4 x dwordx4) + 1 EA float. R12: SGPR-base saddr
// form — x is wave-uniform (readfirstlane), so the slab base lives in an
// SGPR pair computed on the scalar pipe; the VGPR offset is loop-invariant.
// Removes all per-step 64-bit VALU address math. INLINE ASM: volatile loads
// cannot be sunk (round-4 collapse). Counted wait: vmcnt(5) inside STEPX
// (2-deep ring, 10 outstanding at step top; round-5-verified count).
#define PF(XS, D0, D1, D2, D3, EAS) do {                                  \
    const unsigned char* bW_ = W8 + ((size_t)(unsigned)(XS) << 16);       \
    const unsigned char* bE_ = (const unsigned char*)EA                   \
                             + ((size_t)(unsigned)(XS) << 10);            \
    asm volatile("global_load_dwordx4 %0, %5, %7\n\t"                     \
                 "global_load_dwordx4 %1, %5, %7 offset:1024\n\t"         \
                 "global_load_dwordx4 %2, %5, %7 offset:2048\n\t"         \
                 "global_load_dwordx4 %3, %5, %7 offset:3072\n\t"         \
                 "global_load_dword   %4, %6, %8"                         \
                 : "=&v"(D0), "=&v"(D1), "=&v"(D2), "=&v"(D3), "=&v"(EAS) \
                 : "v"(voffW), "v"(voffE), "s"(bW_), "s"(bE_));           \
} while (0)

// One recursion step. Exact for any positive wave-uniform scale (accounted
// in LM). Rescale is PARITY (1-step-stale) — log-level recursion
// m_{t+1} = m_t - m_{t-1} + c has |roots| = 1 exactly (bounded oscillation).
// Deeper staleness is UNSTABLE (|z|=1.15, round-3 failure) — do not deepen.
// Order (r9 hoist): B ds_reads + rs2 read FIRST — their ~120cyc LDS latency
// overlaps the W vmcnt wait — then vmcnt(5) + sched_barrier (stops MFMA
// hoisting past the wait, rule #18), then the 2 scaled MFMAs.
#if HW_MXF8
#define STEPX(XC, W0, W1_, W2_, W3_, EAS) do {                           \
    const u32x4* bv_ = (const u32x4*)u8b[pb];                            \
    u32x4 B0 = bv_[(g << 2) + 0];                                        \
    u32x4 B1 = bv_[(g << 2) + 1];                                        \
    u32x4 B2 = bv_[(g << 2) + 2];                                        \
    u32x4 B3 = bv_[(g << 2) + 3];                                        \
    float rr_ = rs2[pb];                                                 \
    asm volatile("s_waitcnt vmcnt(5)" ::: "memory");                     \
    __builtin_amdgcn_sched_barrier(0);                                   \
    if ((XC) != 0) {                                                     \
        f32x4 ac0 = {0.f, 0.f, 0.f, 0.f}, ac1 = {0.f, 0.f, 0.f, 0.f};    \
        ac0 = __builtin_amdgcn_mfma_scale_f32_16x16x128_f8f6f4(          \
                pk8(W0, W1_), pk8(B0, B1), ac0, 0, 0,                    \
                0, 0x7F7F7F7F, 0, 0x7F7F7F7F);                           \
        ac1 = __builtin_amdgcn_mfma_scale_f32_16x16x128_f8f6f4(          \
                pk8(W2_, W3_), pk8(B2, B3), ac1, 0, 0,                   \
                0, 0x7F7F7F7F, 0, 0x7F7F7F7F);                           \
        f32x4 sv = ac0 + ac1;   /* all 16 cols identical; rows 4g..4g+3 */ \
        float svr = (r_ == 0) ? sv.x : (r_ == 1) ? sv.y                  \
                  : (r_ == 2) ? sv.z : sv.w;                             \
        if (isw) {                                                       \
            float nu = (EAS) * svr * rr_;                                \
            u_lastS = nu;                                                \
            u8c[((pb ^ 1) << 8) + wbyte] = fp8_1(nu);                    \
        }                                                                \
        if (tid == 0) { rs2[pb ^ 1] = 0.0625f / fmaxf(sv.x, 1e-30f);     \
                        LM -= __logf(rr_); }                             \
    } else {                                                             \
        if (isw) u8c[((pb ^ 1) << 8) + wbyte] = u8c[(pb << 8) + wbyte];  \
        if (tid == 0) rs2[pb ^ 1] = rs2[pb];                             \
    }                                                                    \
    pb ^= 1;                                                             \
    sync_lds();                                                          \
} while (0)
#else
#define STEPX(XC, W0, W1_, W2_, W3_, EAS) do {                           \
    const u32x4* bv_ = (const u32x4*)u8b[pb];                            \
    u32x4 B0 = bv_[(g << 2) + 0];                                        \
    u32x4 B1 = bv_[(g << 2) + 1];                                        \
    u32x4 B2 = bv_[(g << 2) + 2];                                        \
    u32x4 B3 = bv_[(g << 2) + 3];                                        \
    float rr_ = rs2[pb];                                                 \
    asm volatile("s_waitcnt vmcnt(5)" ::: "memory");                     \
    __builtin_amdgcn_sched_barrier(0);                                   \
    if ((XC) != 0) {                                                     \
        f32x4 ac0 = {0.f, 0.f, 0.f, 0.f}, ac1 = {0.f, 0.f, 0.f, 0.f};    \
        ac0 = __builtin_amdgcn_mfma_f32_16x16x32_fp8_fp8(mk64(W0[0], W0[1]),   mk64(B0[0], B0[1]), ac0, 0, 0, 0); \
        ac1 = __builtin_amdgcn_mfma_f32_16x16x32_fp8_fp8(mk64(W0[2], W0[3]),   mk64(B0[2], B0[3]), ac1, 0, 0, 0); \
        ac0 = __builtin_amdgcn_mfma_f32_16x16x32_fp8_fp8(mk64(W1_[0], W1_[1]), mk64(B1[0], B1[1]), ac0, 0, 0, 0); \
        ac1 = __builtin_amdgcn_mfma_f32_16x16x32_fp8_fp8(mk64(W1_[2], W1_[3]), mk64(B1[2], B1[3]), ac1, 0, 0, 0); \
        ac0 = __builtin_amdgcn_mfma_f32_16x16x32_fp8_fp8(mk64(W2_[0], W2_[1]), mk64(B2[0], B2[1]), ac0, 0, 0, 0); \
        ac1 = __builtin_amdgcn_mfma_f32_16x16x32_fp8_fp8(mk64(W2_[2], W2_[3]), mk64(B2[2], B2[3]), ac1, 0, 0, 0); \
        ac0 = __builtin_amdgcn_mfma_f32_16x16x32_fp8_fp8(mk64(W3_[0], W3_[1]), mk64(B3[0], B3[1]), ac0, 0, 0, 0); \
        ac1 = __builtin_amdgcn_mfma_f32_16x16x32_fp8_fp8(mk64(W3_[2], W3_[3]), mk64(B3[2], B3[3]), ac1, 0, 0, 0); \
        f32x4 sv = ac0 + ac1;                                            \
        float svr = (r_ == 0) ? sv.x : (r_ == 1) ? sv.y                  \
                  : (r_ == 2) ? sv.z : sv.w;                             \
        if (isw) {                                                       \
            float nu = (EAS) * svr * rr_;                                \
            u_lastS = nu;                                                \
            u8c[((pb ^ 1) << 8) + wbyte] = fp8_1(nu);                    \
        }                                                                \
        if (tid == 0) { rs2[pb ^ 1] = 0.0625f / fmaxf(sv.x, 1e-30f);     \
                        LM -= __logf(rr_); }                             \
    } else {                                                             \
        if (isw) u8c[((pb ^ 1) << 8) + wbyte] = u8c[(pb << 8) + wbyte];  \
        if (tid == 0) rs2[pb ^ 1] = rs2[pb];                             \
    }                                                                    \
    pb ^= 1;                                                             \
    sync_lds();                                                          \
} while (0)
#endif

// ---- main recursion: 16 waves, wave w owns q-tile [16w,16w+16).
// Per step: 2 x mfma_scale_f32_16x16x128 (fp8 x fp8, K=256, scale=1.0).
// W + EA register-prefetched TWO steps ahead via volatile-asm saddr loads
// (SGPR slab base, invariant VGPR offset); vmcnt(5) inside each step after
// the hoisted B ds_reads. ----
__global__ __launch_bounds__(1024) void k_main_fast(const int* xs, const unsigned char* W8,
                                                    const float* EA, const float* LOm,
                                                    const float* LAl, float* per_seq) {
    int b = blockIdx.x, tid = threadIdx.x;
    int lane = tid & 63, w = tid >> 6, g = lane >> 4;
    int r_ = lane & 3;
    __shared__ int xsh[LDIM];
    __shared__ float red[4];
    __shared__ float rs2[2];
    __shared__ float lm_sh;
    __shared__ __align__(16) unsigned int u8b[2][64];   // fp8 u, frag order
    __shared__ __align__(16) float u_f[256];            // final u (f32)
    unsigned char* u8c = (unsigned char*)u8b;
    if (tid < LDIM) xsh[tid] = xs[b * LDIM + tid];
    if (tid < 64) {
        // dword d covers n = 32c + 8gg + j0 .. +3
        int gg = tid >> 4, cch = (tid >> 1) & 7, j0 = (tid & 1) << 2;
        int n0 = (cch << 5) + (gg << 3) + j0;
        float4 lv = *(const float4*)(LOm + n0);
        u8b[0][tid] = pack4_fp8(__expf(lv.x), __expf(lv.y), __expf(lv.z), __expf(lv.w));
    }
    if (tid < 2) rs2[tid] = 0.0625f / 256.0f;
    __syncthreads();

    float LM = 0.f;
    int pb = 0;
    int isw = ((lane & 15) < 4);               // 4 writer lanes per 16-lane col group
    int q0 = (w << 4) + (g << 2);              // this lane's 4-row base
    int wdw = (((q0 >> 3) & 3) << 4) + ((q0 >> 5) << 1) + ((q0 & 7) >> 2);
    int wbyte = (wdw << 2) + r_;               // byte slot of row q0+r_ in u8b
    float u_lastS = 1.f;
    int voffW = (w << 12) + (lane << 4);       // loop-invariant W lane offset
    int voffE = (q0 + r_) << 2;                // loop-invariant EA lane offset

    u32x4 A0, A1, A2, A3, Bb0, Bb1, Bb2, Bb3;
    float eA, eB;
    int x0 = __builtin_amdgcn_readfirstlane(xsh[511]);
    int x1 = __builtin_amdgcn_readfirstlane(xsh[510]);
    PF(x0, A0, A1, A2, A3, eA);
    PF(x1, Bb0, Bb1, Bb2, Bb3, eB);
    for (int it = 0; it < 256; ++it) {
        int pf = 509 - (it << 1);
        int y0 = (pf >= 0) ? __builtin_amdgcn_readfirstlane(xsh[pf])     : 0;
        int y1 = (pf >= 1) ? __builtin_amdgcn_readfirstlane(xsh[pf - 1]) : 0;
        STEPX(x0, A0, A1, A2, A3, eA);     PF(y0, A0, A1, A2, A3, eA);
        STEPX(x1, Bb0, Bb1, Bb2, Bb3, eB); PF(y1, Bb0, Bb1, Bb2, Bb3, eB);
        x0 = y0; x1 = y1;
    }
    asm volatile("s_waitcnt vmcnt(0)" ::: "memory");   // drain dangling loads

    // per_seq[b] = LM + lse_q(LAl[q] + log u[q]); u_lastS is from the last
    // non-skip step (f32, pre-quantization).
    if (isw) u_f[q0 + r_] = u_lastS;
    if (tid == 0) lm_sh = LM;
    __syncthreads();
    float v = -3.0e38f;
    if (tid < 256) v = LAl[tid] + __logf(fmaxf(u_f[tid], 1e-37f));
    float m2 = wred_max(v);
    if (tid < 256 && (tid & 63) == 0) red[tid >> 6] = m2;
    __syncthreads();
    m2 = fmaxf(fmaxf(red[0], red[1]), fmaxf(red[2], red[3]));
    float e = (tid < 256) ? __expf(v - m2) : 0.f;
    float es = wred_add(e);
    __syncthreads();
    if (tid < 256 && (tid & 63) == 0) red[tid >> 6] = es;
    __syncthreads();
    if (tid == 0) per_seq[b] = lm_sh + m2 + __logf(red[0] + red[1] + red[2] + red[3]);
}

// ---- fallback (small ws): read T (f32) directly, exp on the fly.
//      EA holds exp(A), so take logf of it. ----
__global__ __launch_bounds__(256) void k_main_med(const int* xs, const float* T,
                                                  const float* A, const float* LOm,
                                                  const float* LAl, float* per_seq) {
    int b = blockIdx.x, q = threadIdx.x;
    __shared__ int xsh[LDIM];
    __shared__ float red[4];
    __shared__ __align__(16) float u_f[256];
    for (int i = q; i < LDIM; i += 256) xsh[i] = xs[b * LDIM + i];
    float c = LOm[q];
    __syncthreads();
    for (int t = LDIM - 1; t >= 0; --t) {
        int x = xsh[t];
        if (x != 0) {
            float m = wred_max(c);
            if ((q & 63) == 0) red[q >> 6] = m;
            __syncthreads();
            m = fmaxf(fmaxf(red[0], red[1]), fmaxf(red[2], red[3]));
            u_f[q] = __expf(c - m);
            __syncthreads();
            const float* Tp = T + (((size_t)(q << 8) + (size_t)x) << 8);
            float acc = 0.f;
            #pragma unroll 4
            for (int i = 0; i < 32; ++i) {
                float4 ta = *(const float4*)(Tp + (i << 3));
                float4 tb = *(const float4*)(Tp + (i << 3) + 4);
                float4 ua = *(const float4*)(u_f + (i << 3));
                float4 ub = *(const float4*)(u_f + (i << 3) + 4);
                acc = fmaf(__expf(-ta.x), ua.x, acc);
                acc = fmaf(__expf(-ta.y), ua.y, acc);
                acc = fmaf(__expf(-ta.z), ua.z, acc);
                acc = fmaf(__expf(-ta.w), ua.w, acc);
                acc = fmaf(__expf(-tb.x), ub.x, acc);
                acc = fmaf(__expf(-tb.y), ub.y, acc);
                acc = fmaf(__expf(-tb.z), ub.z, acc);
                acc = fmaf(__expf(-tb.w), ub.w, acc);
            }
            acc = fmaxf(acc, 1e-30f);
            c = __logf(A[(x << 8) + q]) + m + __logf(acc);
        }
    }
    float v = LAl[q] + c;
    float m2 = wred_max(v);
    if ((q & 63) == 0) red[q >> 6] = m2;
    __syncthreads();
    m2 = fmaxf(fmaxf(red[0], red[1]), fmaxf(red[2], red[3]));
    float es = wred_add(__expf(v - m2));
    __syncthreads();
    if ((q & 63) == 0) red[q >> 6] = es;
    __syncthreads();
    if (q == 0) per_seq[b] = m2 + __logf(red[0] + red[1] + red[2] + red[3]);
}

__global__ __launch_bounds__(64) void k_final(const float* per_seq, float* out) {
    if (threadIdx.x == 0) {
        float s = 0.f;
        for (int i = 0; i < BDIM; ++i) s += per_seq[i];
        out[0] = s;
    }
}

extern "C" void kernel_launch(void* const* d_in, const int* in_sizes, int n_in,
                              void* d_out, int out_size, void* d_ws, size_t ws_size,
                              hipStream_t stream) {
    const int* xs = nullptr;
    const float *alpha = nullptr, *omega = nullptr, *E = nullptr, *T = nullptr;
    int seen256 = 0;
    for (int i = 0; i < n_in; ++i) {
        int s = in_sizes[i];
        if      (s == 16777216) T  = (const float*)d_in[i];
        else if (s == 65536)    E  = (const float*)d_in[i];
        else if (s == 8192)     xs = (const int*)d_in[i];
        else if (s == 256) { if (seen256++ == 0) alpha = (const float*)d_in[i];
                             else                omega = (const float*)d_in[i]; }
    }

    char* ws = (char*)d_ws;
    float* EA       = (float*)(ws + WS_A);
    float* cE       = (float*)(ws + WS_CE);
    float* LOm      = (float*)(ws + WS_LOM);
    float* LAl      = (float*)(ws + WS_LAL);
    float* per_seq  = (float*)(ws + WS_PS);
    unsigned char* W8 = (unsigned char*)(ws + WS_W);
    int fast = (ws_size >= WS_FAST_BYTES) ? 1 : 0;

    k_erow<<<65, 256, 0, stream>>>(E, omega, alpha, cE, LOm, LAl);
    k_trow<<<4096, 1024, 0, stream>>>(T, E, cE, W8, EA, fast);
    if (fast) k_main_fast<<<BDIM, 1024, 0, stream>>>(xs, W8, EA, LOm, LAl, per_seq);
    else      k_main_med <<<BDIM, 256, 0, stream>>>(xs, T, EA, LOm, LAl, per_seq);
    k_final<<<1, 64, 0, stream>>>(per_seq, (float*)d_out);
}

// Round 14
// 457.925 us; speedup vs baseline: 1.0476x; 1.0476x over previous
//
#include <hip/hip_runtime.h>
#include <hip/hip_fp16.h>

#define LDIM 512
#define BDIM 16

// ws layout: small arrays first so the fallback path works with small ws.
#define WS_A    0u          // 262144 B  (float EA[256*256], EA[x*256+q] = exp(A))
#define WS_CE   262144u     // 1024 B
#define WS_LOM  263168u     // 1024 B
#define WS_LAL  264192u     // 1024 B
#define WS_PS   265216u     // 64 B
#define WS_W    270336u     // 16777216 B (fp8 W, MFMA fragment layout), 16B aligned
#define WS_FAST_BYTES (270336ull + 16777216ull)

typedef float f32x4 __attribute__((ext_vector_type(4)));
typedef int   i32x8 __attribute__((ext_vector_type(8)));
typedef unsigned int u32x4 __attribute__((ext_vector_type(4)));

__device__ __forceinline__ float wred_add(float v) {
    #pragma unroll
    for (int off = 32; off; off >>= 1) v += __shfl_xor(v, off);
    return v;
}
__device__ __forceinline__ float wred_max(float v) {
    #pragma unroll
    for (int off = 32; off; off >>= 1) v = fmaxf(v, __shfl_xor(v, off));
    return v;
}

#if __has_builtin(__builtin_amdgcn_cvt_pk_f32_fp8) && __has_builtin(__builtin_amdgcn_cvt_pk_fp8_f32)
#define HW_FP8 1
#else
#define HW_FP8 0
#endif
#if __has_builtin(__builtin_amdgcn_mfma_scale_f32_16x16x128_f8f6f4)
#define HW_MXF8 1
#else
#define HW_MXF8 0
#endif

// Fallback software e4m3fn (normals only).
__device__ __forceinline__ unsigned int sw_fp8_enc(float a) {
    union { float f; unsigned int u; } x; x.f = a;
    unsigned int u = x.u + 0x80000u;               // round at mantissa bit 19
    return (((u >> 23) & 0xffu) - 120u) * 8u + ((u >> 20) & 7u);
}
__device__ __forceinline__ unsigned int pack4_fp8(float a, float b, float c, float d) {
#if HW_FP8
    int v = 0;
    v = __builtin_amdgcn_cvt_pk_fp8_f32(a, b, v, false);   // bytes 0,1
    v = __builtin_amdgcn_cvt_pk_fp8_f32(c, d, v, true);    // bytes 2,3
    return (unsigned int)v;
#else
    return sw_fp8_enc(a) | (sw_fp8_enc(b) << 8) | (sw_fp8_enc(c) << 16) | (sw_fp8_enc(d) << 24);
#endif
}
__device__ __forceinline__ unsigned char fp8_1(float a) {
#if HW_FP8
    return (unsigned char)(__builtin_amdgcn_cvt_pk_fp8_f32(a, a, 0, false) & 0xff);
#else
    return (unsigned char)sw_fp8_enc(a);
#endif
}

__device__ __forceinline__ long mk64(unsigned int lo, unsigned int hi) {
    return (long)(((unsigned long long)hi << 32) | (unsigned long long)lo);
}
__device__ __forceinline__ i32x8 pk8(u32x4 a, u32x4 b) {
    i32x8 r;
    r[0] = (int)a[0]; r[1] = (int)a[1]; r[2] = (int)a[2]; r[3] = (int)a[3];
    r[4] = (int)b[0]; r[5] = (int)b[1]; r[6] = (int)b[2]; r[7] = (int)b[3];
    return r;
}

// Raw barrier: only drains LDS (lgkmcnt). Global prefetch loads stay in
// flight across it. sched_barrier(0) fences pin compile-time ordering.
__device__ __forceinline__ void sync_lds() {
    asm volatile("s_waitcnt lgkmcnt(0)" ::: "memory");
    __builtin_amdgcn_sched_barrier(0);
    __builtin_amdgcn_s_barrier();
    __builtin_amdgcn_sched_barrier(0);
    asm volatile("" ::: "memory");
}

// Michelot exact sparsemax over a wave's 256 values (4 per lane).
// Returns c = <z,p*> - 0.5||p*||^2 + 0.5 (wave-uniform).
// R14: the support-count reduction uses ballot+popcount (v_cmp + scalar
// s_bcnt1_b64, 0 DS ops) instead of a shfl tree — halves per-iteration
// DS-pipe traffic (12 -> 6 ds ops). Numerically identical (cnt was always
// an exact small integer; same support set -> same tau sequence).
__device__ float sparsemax_c4(float z0, float z1, float z2, float z3) {
    float ssum = wred_add(z0 + z1 + z2 + z3);
    float tau = (ssum - 1.0f) * (1.0f / 256.0f);
    int kprev = 256;
    for (int it = 0; it < 64; ++it) {
        float s = 0.f;
        if (z0 > tau) s += z0;
        if (z1 > tau) s += z1;
        if (z2 > tau) s += z2;
        if (z3 > tau) s += z3;
        s = wred_add(s);
        int k = __popcll(__ballot(z0 > tau)) + __popcll(__ballot(z1 > tau))
              + __popcll(__ballot(z2 > tau)) + __popcll(__ballot(z3 > tau));
        tau = (s - 1.0f) / (float)k;       // k >= 1 invariant (max > tau)
        if (k == kprev) break;
        kprev = k;
    }
    float cs = 0.f, t2 = tau * tau;
    if (z0 > tau) cs += z0 * z0 - t2;
    if (z1 > tau) cs += z1 * z1 - t2;
    if (z2 > tau) cs += z2 * z2 - t2;
    if (z3 > tau) cs += z3 * z3 - t2;
    cs = wred_add(cs);
    return 0.5f * cs + 0.5f;
}

// Rows of E (256) + omega (1) + alpha (1). All float32.
__global__ __launch_bounds__(256) void k_erow(const float* E, const float* omega,
                                              const float* alpha,
                                              float* cE, float* LOm, float* LAl) {
    int wid = blockIdx.x * 4 + (threadIdx.x >> 6);
    if (wid >= 258) return;
    int lane = threadIdx.x & 63;
    const float* row = (wid < 256) ? (E + wid * 256)
                      : (wid == 256 ? omega : alpha);
    float4 z = *(const float4*)(row + lane * 4);
    float c = sparsemax_c4(z.x, z.y, z.z, z.w);
    if (wid < 256) {
        if (lane == 0) cE[wid] = c;
    } else {
        float* dst = (wid == 256) ? LOm : LAl;
        *(float4*)(dst + lane * 4) = make_float4(c - z.x, c - z.y, c - z.z, c - z.w);
    }
}

// wid = x*256+q.  Fused: EA[x*256+q] = exp(c_T(T[q,x,:]) + cE[q] - E[q,x]).
// W8 in MFMA fp8 A-fragment order (round-5-verified for the scaled
// 16x16x128 fp8/fp8 contraction — the per-(group,dword,byte) k-map of A
// equals the k-map of the u8b B-fragments):
//   main-kernel wave w (q-tile 16w..16w+15), lane l, uint4 #i2 reads 16 B at
//     x*65536 + w*4096 + i2*1024 + l*16
//   low 8 B = chunk c=2*i2  (k = 32c + 8*(l>>4) + j, j=0..7), high 8 B = 2*i2+1.
// NOTE (round-8 lesson): do NOT port W to fp6/fp4 — the f8f6f4 sub-byte
// register bit-layout is undocumented and a wrong guess is silent garbage.
// NOTE (round-11 lesson): do NOT deepen the register prefetch ring past 2 —
// SIInsertWaitcnts can't see into inline asm, and at ~128-VGPR pressure the
// allocator copies/spills in-flight asm-load destinations (silent stale data).
// R10: block's 16 waves scatter into a 4-KB LDS buffer, then 256 threads
// store contiguous uint4 (measured neutral vs direct scatter; kept).
__global__ __launch_bounds__(1024) void k_trow(const float* T, const float* E,
                                               const float* cE, unsigned char* W8,
                                               float* EA, int writeW) {
    int tid = threadIdx.x;
    int wid = blockIdx.x * 16 + (tid >> 6);
    int lane = tid & 63;
    int x = wid >> 8, q = wid & 255;
    __shared__ __align__(16) unsigned int wbuf[1024];
    const float* row = T + ((size_t)((q << 8) | x) << 8);
    float4 z = *(const float4*)(row + lane * 4);
    float c = sparsemax_c4(z.x, z.y, z.z, z.w);
    if (writeW) {                              // block-uniform
        unsigned int packed = pack4_fp8(__expf(-z.x), __expf(-z.y),
                                        __expf(-z.z), __expf(-z.w));
        int n0 = lane << 2;                // 4 consecutive n share i2,g,half
        // intra-4KB dword index: i2<<8 | g<<6 | (q&15)<<2 | half<<1 | j0>>2
        int lidx = ((n0 >> 6) << 8) | (((n0 >> 3) & 3) << 6)
                 | ((q & 15) << 2) | (((n0 >> 5) & 1) << 1) | ((n0 & 7) >> 2);
        wbuf[lidx] = packed;
        __syncthreads();
        if (tid < 256) {
            size_t base = ((size_t)x << 16) + ((size_t)(q >> 4) << 12);
            *(uint4*)(W8 + base + ((size_t)tid << 4)) =
                *(const uint4*)((const unsigned char*)wbuf + (tid << 4));
        }
    }
    if (lane == 0) EA[wid] = __expf(c + cE[q] - E[(q << 8) + x]);
}

// Prefetch one step's W (4 x dwordx4) + 1 EA float. R12: SGPR-base saddr
// form — x is wave-uniform (readfirstlane), so the slab base lives in an
// SGPR pair computed on the scalar pipe; the VGPR offset is loop-invariant.
// INLINE ASM: volatile loads cannot be sunk (round-4 collapse). Counted
// wait: vmcnt(5) inside STEPX (2-deep ring, 10 outstanding at step top).
#define PF(XS, D0, D1, D2, D3, EAS) do {                                  \
    const unsigned char* bW_ = W8 + ((size_t)(unsigned)(XS) << 16);       \
    const unsigned char* bE_ = (const unsigned char*)EA                   \
                             + ((size_t)(unsigned)(XS) << 10);            \
    asm volatile("global_load_dwordx4 %0, %5, %7\n\t"                     \
                 "global_load_dwordx4 %1, %5, %7 offset:1024\n\t"         \
                 "global_load_dwordx4 %2, %5, %7 offset:2048\n\t"         \
                 "global_load_dwordx4 %3, %5, %7 offset:3072\n\t"         \
                 "global_load_dword   %4, %6, %8"                         \
                 : "=&v"(D0), "=&v"(D1), "=&v"(D2), "=&v"(D3), "=&v"(EAS) \
                 : "v"(voffW), "v"(voffE), "s"(bW_), "s"(bE_));           \
} while (0)

// One recursion step. Exact for any positive wave-uniform scale (accounted
// in LM). Rescale is PARITY (1-step-stale) — log-level recursion
// m_{t+1} = m_t - m_{t-1} + c has |roots| = 1 exactly (bounded oscillation).
// Deeper staleness is UNSTABLE (|z|=1.15, round-3 failure) — do not deepen.
// Order (r9 hoist): B ds_reads + rs2 read FIRST — their ~120cyc LDS latency
// overlaps the W vmcnt wait — then vmcnt(5) + sched_barrier (stops MFMA
// hoisting past the wait, rule #18), then the 2 scaled MFMAs.
#if HW_MXF8
#define STEPX(XC, W0, W1_, W2_, W3_, EAS) do {                           \
    const u32x4* bv_ = (const u32x4*)u8b[pb];                            \
    u32x4 B0 = bv_[(g << 2) + 0];                                        \
    u32x4 B1 = bv_[(g << 2) + 1];                                        \
    u32x4 B2 = bv_[(g << 2) + 2];                                        \
    u32x4 B3 = bv_[(g << 2) + 3];                                        \
    float rr_ = rs2[pb];                                                 \
    asm volatile("s_waitcnt vmcnt(5)" ::: "memory");                     \
    __builtin_amdgcn_sched_barrier(0);                                   \
    if ((XC) != 0) {                                                     \
        f32x4 ac0 = {0.f, 0.f, 0.f, 0.f}, ac1 = {0.f, 0.f, 0.f, 0.f};    \
        ac0 = __builtin_amdgcn_mfma_scale_f32_16x16x128_f8f6f4(          \
                pk8(W0, W1_), pk8(B0, B1), ac0, 0, 0,                    \
                0, 0x7F7F7F7F, 0, 0x7F7F7F7F);                           \
        ac1 = __builtin_amdgcn_mfma_scale_f32_16x16x128_f8f6f4(          \
                pk8(W2_, W3_), pk8(B2, B3), ac1, 0, 0,                   \
                0, 0x7F7F7F7F, 0, 0x7F7F7F7F);                           \
        f32x4 sv = ac0 + ac1;   /* all 16 cols identical; rows 4g..4g+3 */ \
        float svr = (r_ == 0) ? sv.x : (r_ == 1) ? sv.y                  \
                  : (r_ == 2) ? sv.z : sv.w;                             \
        if (isw) {                                                       \
            float nu = (EAS) * svr * rr_;                                \
            u_lastS = nu;                                                \
            u8c[((pb ^ 1) << 8) + wbyte] = fp8_1(nu);                    \
        }                                                                \
        if (tid == 0) { rs2[pb ^ 1] = 0.0625f / fmaxf(sv.x, 1e-30f);     \
                        LM -= __logf(rr_); }                             \
    } else {                                                             \
        if (isw) u8c[((pb ^ 1) << 8) + wbyte] = u8c[(pb << 8) + wbyte];  \
        if (tid == 0) rs2[pb ^ 1] = rs2[pb];                             \
    }                                                                    \
    pb ^= 1;                                                             \
    sync_lds();                                                          \
} while (0)
#else
#define STEPX(XC, W0, W1_, W2_, W3_, EAS) do {                           \
    const u32x4* bv_ = (const u32x4*)u8b[pb];                            \
    u32x4 B0 = bv_[(g << 2) + 0];                                        \
    u32x4 B1 = bv_[(g << 2) + 1];                                        \
    u32x4 B2 = bv_[(g << 2) + 2];                                        \
    u32x4 B3 = bv_[(g << 2) + 3];                                        \
    float rr_ = rs2[pb];                                                 \
    asm volatile("s_waitcnt vmcnt(5)" ::: "memory");                     \
    __builtin_amdgcn_sched_barrier(0);                                   \
    if ((XC) != 0) {                                                     \
        f32x4 ac0 = {0.f, 0.f, 0.f, 0.f}, ac1 = {0.f, 0.f, 0.f, 0.f};    \
        ac0 = __builtin_amdgcn_mfma_f32_16x16x32_fp8_fp8(mk64(W0[0], W0[1]),   mk64(B0[0], B0[1]), ac0, 0, 0, 0); \
        ac1 = __builtin_amdgcn_mfma_f32_16x16x32_fp8_fp8(mk64(W0[2], W0[3]),   mk64(B0[2], B0[3]), ac1, 0, 0, 0); \
        ac0 = __builtin_amdgcn_mfma_f32_16x16x32_fp8_fp8(mk64(W1_[0], W1_[1]), mk64(B1[0], B1[1]), ac0, 0, 0, 0); \
        ac1 = __builtin_amdgcn_mfma_f32_16x16x32_fp8_fp8(mk64(W1_[2], W1_[3]), mk64(B1[2], B1[3]), ac1, 0, 0, 0); \
        ac0 = __builtin_amdgcn_mfma_f32_16x16x32_fp8_fp8(mk64(W2_[0], W2_[1]), mk64(B2[0], B2[1]), ac0, 0, 0, 0); \
        ac1 = __builtin_amdgcn_mfma_f32_16x16x32_fp8_fp8(mk64(W2_[2], W2_[3]), mk64(B2[2], B2[3]), ac1, 0, 0, 0); \
        ac0 = __builtin_amdgcn_mfma_f32_16x16x32_fp8_fp8(mk64(W3_[0], W3_[1]), mk64(B3[0], B3[1]), ac0, 0, 0, 0); \
        ac1 = __builtin_amdgcn_mfma_f32_16x16x32_fp8_fp8(mk64(W3_[2], W3_[3]), mk64(B3[2], B3[3]), ac1, 0, 0, 0); \
        f32x4 sv = ac0 + ac1;                                            \
        float svr = (r_ == 0) ? sv.x : (r_ == 1) ? sv.y                  \
                  : (r_ == 2) ? sv.z : sv.w;                             \
        if (isw) {                                                       \
            float nu = (EAS) * svr * rr_;                                \
            u_lastS = nu;                                                \
            u8c[((pb ^ 1) << 8) + wbyte] = fp8_1(nu);                    \
        }                                                                \
        if (tid == 0) { rs2[pb ^ 1] = 0.0625f / fmaxf(sv.x, 1e-30f);     \
                        LM -= __logf(rr_); }                             \
    } else {                                                             \
        if (isw) u8c[((pb ^ 1) << 8) + wbyte] = u8c[(pb << 8) + wbyte];  \
        if (tid == 0) rs2[pb ^ 1] = rs2[pb];                             \
    }                                                                    \
    pb ^= 1;                                                             \
    sync_lds();                                                          \
} while (0)
#endif

// ---- main recursion: 16 waves, wave w owns q-tile [16w,16w+16).
// Per step: 2 x mfma_scale_f32_16x16x128 (fp8 x fp8, K=256, scale=1.0).
// W + EA register-prefetched TWO steps ahead via volatile-asm saddr loads
// (SGPR slab base, invariant VGPR offset); vmcnt(5) inside each step after
// the hoisted B ds_reads. At its structural floor (r13): step ~1540 cyc ≈
// max(TCP fill 64KB/step ~1024 cyc, serial barrier+LDS+MFMA chain). ----
__global__ __launch_bounds__(1024) void k_main_fast(const int* xs, const unsigned char* W8,
                                                    const float* EA, const float* LOm,
                                                    const float* LAl, float* per_seq) {
    int b = blockIdx.x, tid = threadIdx.x;
    int lane = tid & 63, w = tid >> 6, g = lane >> 4;
    int r_ = lane & 3;
    __shared__ int xsh[LDIM];
    __shared__ float red[4];
    __shared__ float rs2[2];
    __shared__ float lm_sh;
    __shared__ __align__(16) unsigned int u8b[2][64];   // fp8 u, frag order
    __shared__ __align__(16) float u_f[256];            // final u (f32)
    unsigned char* u8c = (unsigned char*)u8b;
    if (tid < LDIM) xsh[tid] = xs[b * LDIM + tid];
    if (tid < 64) {
        // dword d covers n = 32c + 8gg + j0 .. +3
        int gg = tid >> 4, cch = (tid >> 1) & 7, j0 = (tid & 1) << 2;
        int n0 = (cch << 5) + (gg << 3) + j0;
        float4 lv = *(const float4*)(LOm + n0);
        u8b[0][tid] = pack4_fp8(__expf(lv.x), __expf(lv.y), __expf(lv.z), __expf(lv.w));
    }
    if (tid < 2) rs2[tid] = 0.0625f / 256.0f;
    __syncthreads();

    float LM = 0.f;
    int pb = 0;
    int isw = ((lane & 15) < 4);               // 4 writer lanes per 16-lane col group
    int q0 = (w << 4) + (g << 2);              // this lane's 4-row base
    int wdw = (((q0 >> 3) & 3) << 4) + ((q0 >> 5) << 1) + ((q0 & 7) >> 2);
    int wbyte = (wdw << 2) + r_;               // byte slot of row q0+r_ in u8b
    float u_lastS = 1.f;
    int voffW = (w << 12) + (lane << 4);       // loop-invariant W lane offset
    int voffE = (q0 + r_) << 2;                // loop-invariant EA lane offset

    u32x4 A0, A1, A2, A3, Bb0, Bb1, Bb2, Bb3;
    float eA, eB;
    int x0 = __builtin_amdgcn_readfirstlane(xsh[511]);
    int x1 = __builtin_amdgcn_readfirstlane(xsh[510]);
    PF(x0, A0, A1, A2, A3, eA);
    PF(x1, Bb0, Bb1, Bb2, Bb3, eB);
    for (int it = 0; it < 256; ++it) {
        int pf = 509 - (it << 1);
        int y0 = (pf >= 0) ? __builtin_amdgcn_readfirstlane(xsh[pf])     : 0;
        int y1 = (pf >= 1) ? __builtin_amdgcn_readfirstlane(xsh[pf - 1]) : 0;
        STEPX(x0, A0, A1, A2, A3, eA);     PF(y0, A0, A1, A2, A3, eA);
        STEPX(x1, Bb0, Bb1, Bb2, Bb3, eB); PF(y1, Bb0, Bb1, Bb2, Bb3, eB);
        x0 = y0; x1 = y1;
    }
    asm volatile("s_waitcnt vmcnt(0)" ::: "memory");   // drain dangling loads

    // per_seq[b] = LM + lse_q(LAl[q] + log u[q]); u_lastS is from the last
    // non-skip step (f32, pre-quantization).
    if (isw) u_f[q0 + r_] = u_lastS;
    if (tid == 0) lm_sh = LM;
    __syncthreads();
    float v = -3.0e38f;
    if (tid < 256) v = LAl[tid] + __logf(fmaxf(u_f[tid], 1e-37f));
    float m2 = wred_max(v);
    if (tid < 256 && (tid & 63) == 0) red[tid >> 6] = m2;
    __syncthreads();
    m2 = fmaxf(fmaxf(red[0], red[1]), fmaxf(red[2], red[3]));
    float e = (tid < 256) ? __expf(v - m2) : 0.f;
    float es = wred_add(e);
    __syncthreads();
    if (tid < 256 && (tid & 63) == 0) red[tid >> 6] = es;
    __syncthreads();
    if (tid == 0) per_seq[b] = lm_sh + m2 + __logf(red[0] + red[1] + red[2] + red[3]);
}

// ---- fallback (small ws): read T (f32) directly, exp on the fly.
//      EA holds exp(A), so take logf of it. ----
__global__ __launch_bounds__(256) void k_main_med(const int* xs, const float* T,
                                                  const float* A, const float* LOm,
                                                  const float* LAl, float* per_seq) {
    int b = blockIdx.x, q = threadIdx.x;
    __shared__ int xsh[LDIM];
    __shared__ float red[4];
    __shared__ __align__(16) float u_f[256];
    for (int i = q; i < LDIM; i += 256) xsh[i] = xs[b * LDIM + i];
    float c = LOm[q];
    __syncthreads();
    for (int t = LDIM - 1; t >= 0; --t) {
        int x = xsh[t];
        if (x != 0) {
            float m = wred_max(c);
            if ((q & 63) == 0) red[q >> 6] = m;
            __syncthreads();
            m = fmaxf(fmaxf(red[0], red[1]), fmaxf(red[2], red[3]));
            u_f[q] = __expf(c - m);
            __syncthreads();
            const float* Tp = T + (((size_t)(q << 8) + (size_t)x) << 8);
            float acc = 0.f;
            #pragma unroll 4
            for (int i = 0; i < 32; ++i) {
                float4 ta = *(const float4*)(Tp + (i << 3));
                float4 tb = *(const float4*)(Tp + (i << 3) + 4);
                float4 ua = *(const float4*)(u_f + (i << 3));
                float4 ub = *(const float4*)(u_f + (i << 3) + 4);
                acc = fmaf(__expf(-ta.x), ua.x, acc);
                acc = fmaf(__expf(-ta.y), ua.y, acc);
                acc = fmaf(__expf(-ta.z), ua.z, acc);
                acc = fmaf(__expf(-ta.w), ua.w, acc);
                acc = fmaf(__expf(-tb.x), ub.x, acc);
                acc = fmaf(__expf(-tb.y), ub.y, acc);
                acc = fmaf(__expf(-tb.z), ub.z, acc);
                acc = fmaf(__expf(-tb.w), ub.w, acc);
            }
            acc = fmaxf(acc, 1e-30f);
            c = __logf(A[(x << 8) + q]) + m + __logf(acc);
        }
    }
    float v = LAl[q] + c;
    float m2 = wred_max(v);
    if ((q & 63) == 0) red[q >> 6] = m2;
    __syncthreads();
    m2 = fmaxf(fmaxf(red[0], red[1]), fmaxf(red[2], red[3]));
    float es = wred_add(__expf(v - m2));
    __syncthreads();
    if ((q & 63) == 0) red[q >> 6] = es;
    __syncthreads();
    if (q == 0) per_seq[b] = m2 + __logf(red[0] + red[1] + red[2] + red[3]);
}

__global__ __launch_bounds__(64) void k_final(const float* per_seq, float* out) {
    if (threadIdx.x == 0) {
        float s = 0.f;
        for (int i = 0; i < BDIM; ++i) s += per_seq[i];
        out[0] = s;
    }
}

extern "C" void kernel_launch(void* const* d_in, const int* in_sizes, int n_in,
                              void* d_out, int out_size, void* d_ws, size_t ws_size,
                              hipStream_t stream) {
    const int* xs = nullptr;
    const float *alpha = nullptr, *omega = nullptr, *E = nullptr, *T = nullptr;
    int seen256 = 0;
    for (int i = 0; i < n_in; ++i) {
        int s = in_sizes[i];
        if      (s == 16777216) T  = (const float*)d_in[i];
        else if (s == 65536)    E  = (const float*)d_in[i];
        else if (s == 8192)     xs = (const int*)d_in[i];
        else if (s == 256) { if (seen256++ == 0) alpha = (const float*)d_in[i];
                             else                omega = (const float*)d_in[i]; }
    }

    char* ws = (char*)d_ws;
    float* EA       = (float*)(ws + WS_A);
    float* cE       = (float*)(ws + WS_CE);
    float* LOm      = (float*)(ws + WS_LOM);
    float* LAl      = (float*)(ws + WS_LAL);
    float* per_seq  = (float*)(ws + WS_PS);
    unsigned char* W8 = (unsigned char*)(ws + WS_W);
    int fast = (ws_size >= WS_FAST_BYTES) ? 1 : 0;

    k_erow<<<65, 256, 0, stream>>>(E, omega, alpha, cE, LOm, LAl);
    k_trow<<<4096, 1024, 0, stream>>>(T, E, cE, W8, EA, fast);
    if (fast) k_main_fast<<<BDIM, 1024, 0, stream>>>(xs, W8, EA, LOm, LAl, per_seq);
    else      k_main_med <<<BDIM, 256, 0, stream>>>(xs, T, EA, LOm, LAl, per_seq);
    k_final<<<1, 64, 0, stream>>>(per_seq, (float*)d_out);
}

// Round 15
// 447.813 us; speedup vs baseline: 1.0712x; 1.0226x over previous
//
#include <hip/hip_runtime.h>
#include <hip/hip_fp16.h>

#define LDIM 512
#define BDIM 16

// ws layout: small arrays first so the fallback path works with small ws.
#define WS_A    0u          // 262144 B  (float EA[256*256], EA[x*256+q] = exp(A))
#define WS_CE   262144u     // 1024 B
#define WS_LOM  263168u     // 1024 B
#define WS_LAL  264192u     // 1024 B
#define WS_PS   265216u     // 64 B
#define WS_W    270336u     // 16777216 B (fp8 W, MFMA fragment layout), 16B aligned
#define WS_FAST_BYTES (270336ull + 16777216ull)

typedef float f32x4 __attribute__((ext_vector_type(4)));
typedef int   i32x8 __attribute__((ext_vector_type(8)));
typedef unsigned int u32x4 __attribute__((ext_vector_type(4)));

__device__ __forceinline__ float wred_add(float v) {
    #pragma unroll
    for (int off = 32; off; off >>= 1) v += __shfl_xor(v, off);
    return v;
}
__device__ __forceinline__ float wred_max(float v) {
    #pragma unroll
    for (int off = 32; off; off >>= 1) v = fmaxf(v, __shfl_xor(v, off));
    return v;
}

// R15: wave64 float sum on the VALU pipe via DPP (0 DS ops, ~4cyc dependent
// latency vs ~35cyc ds_swizzle). Canonical GCN sequence: after the 6 adds,
// lane 63 holds the full sum; readlane broadcasts it. s_nop 1 between
// dependent DPP ops (VALU-write -> DPP-read hazard; the compiler cannot see
// inside the asm block, so the wait states are manual — r11-class lesson).
__device__ __forceinline__ float dpp_sum(float v) {
    float r = v;
    asm volatile(
        "s_nop 1\n\t"
        "v_add_f32 %0, %0, %0 row_shr:1 row_mask:0xf bank_mask:0xf bound_ctrl:0\n\t"
        "s_nop 1\n\t"
        "v_add_f32 %0, %0, %0 row_shr:2 row_mask:0xf bank_mask:0xf bound_ctrl:0\n\t"
        "s_nop 1\n\t"
        "v_add_f32 %0, %0, %0 row_shr:4 row_mask:0xf bank_mask:0xe\n\t"
        "s_nop 1\n\t"
        "v_add_f32 %0, %0, %0 row_shr:8 row_mask:0xf bank_mask:0xc\n\t"
        "s_nop 1\n\t"
        "v_add_f32 %0, %0, %0 row_bcast:15 row_mask:0xa bank_mask:0xf\n\t"
        "s_nop 1\n\t"
        "v_add_f32 %0, %0, %0 row_bcast:31 row_mask:0xc bank_mask:0xf\n\t"
        "s_nop 1"
        : "+v"(r));
    return __int_as_float(__builtin_amdgcn_readlane(__float_as_int(r), 63));
}

#if __has_builtin(__builtin_amdgcn_cvt_pk_f32_fp8) && __has_builtin(__builtin_amdgcn_cvt_pk_fp8_f32)
#define HW_FP8 1
#else
#define HW_FP8 0
#endif
#if __has_builtin(__builtin_amdgcn_mfma_scale_f32_16x16x128_f8f6f4)
#define HW_MXF8 1
#else
#define HW_MXF8 0
#endif

// Fallback software e4m3fn (normals only).
__device__ __forceinline__ unsigned int sw_fp8_enc(float a) {
    union { float f; unsigned int u; } x; x.f = a;
    unsigned int u = x.u + 0x80000u;               // round at mantissa bit 19
    return (((u >> 23) & 0xffu) - 120u) * 8u + ((u >> 20) & 7u);
}
__device__ __forceinline__ unsigned int pack4_fp8(float a, float b, float c, float d) {
#if HW_FP8
    int v = 0;
    v = __builtin_amdgcn_cvt_pk_fp8_f32(a, b, v, false);   // bytes 0,1
    v = __builtin_amdgcn_cvt_pk_fp8_f32(c, d, v, true);    // bytes 2,3
    return (unsigned int)v;
#else
    return sw_fp8_enc(a) | (sw_fp8_enc(b) << 8) | (sw_fp8_enc(c) << 16) | (sw_fp8_enc(d) << 24);
#endif
}
__device__ __forceinline__ unsigned char fp8_1(float a) {
#if HW_FP8
    return (unsigned char)(__builtin_amdgcn_cvt_pk_fp8_f32(a, a, 0, false) & 0xff);
#else
    return (unsigned char)sw_fp8_enc(a);
#endif
}

__device__ __forceinline__ long mk64(unsigned int lo, unsigned int hi) {
    return (long)(((unsigned long long)hi << 32) | (unsigned long long)lo);
}
__device__ __forceinline__ i32x8 pk8(u32x4 a, u32x4 b) {
    i32x8 r;
    r[0] = (int)a[0]; r[1] = (int)a[1]; r[2] = (int)a[2]; r[3] = (int)a[3];
    r[4] = (int)b[0]; r[5] = (int)b[1]; r[6] = (int)b[2]; r[7] = (int)b[3];
    return r;
}

// Raw barrier: only drains LDS (lgkmcnt). Global prefetch loads stay in
// flight across it. sched_barrier(0) fences pin compile-time ordering.
__device__ __forceinline__ void sync_lds() {
    asm volatile("s_waitcnt lgkmcnt(0)" ::: "memory");
    __builtin_amdgcn_sched_barrier(0);
    __builtin_amdgcn_s_barrier();
    __builtin_amdgcn_sched_barrier(0);
    asm volatile("" ::: "memory");
}

// Michelot exact sparsemax over a wave's 256 values (4 per lane).
// Returns c = <z,p*> - 0.5||p*||^2 + 0.5 (wave-uniform).
// R14: support-count via ballot+popcount (0 DS ops). R15: float sums via
// DPP on the VALU pipe (0 DS ops) — the sparsemax loop now issues zero
// LDS-pipe operations. Numerics: DPP tree sums in a different order than
// the old shfl tree (last-bit differences only; threshold is ~1e3).
__device__ float sparsemax_c4(float z0, float z1, float z2, float z3) {
    float ssum = dpp_sum(z0 + z1 + z2 + z3);
    float tau = (ssum - 1.0f) * (1.0f / 256.0f);
    int kprev = 256;
    for (int it = 0; it < 64; ++it) {
        float s = 0.f;
        if (z0 > tau) s += z0;
        if (z1 > tau) s += z1;
        if (z2 > tau) s += z2;
        if (z3 > tau) s += z3;
        s = dpp_sum(s);
        int k = __popcll(__ballot(z0 > tau)) + __popcll(__ballot(z1 > tau))
              + __popcll(__ballot(z2 > tau)) + __popcll(__ballot(z3 > tau));
        tau = (s - 1.0f) / (float)k;       // k >= 1 invariant (max > tau)
        if (k == kprev) break;
        kprev = k;
    }
    float cs = 0.f, t2 = tau * tau;
    if (z0 > tau) cs += z0 * z0 - t2;
    if (z1 > tau) cs += z1 * z1 - t2;
    if (z2 > tau) cs += z2 * z2 - t2;
    if (z3 > tau) cs += z3 * z3 - t2;
    cs = dpp_sum(cs);
    return 0.5f * cs + 0.5f;
}

// Rows of E (256) + omega (1) + alpha (1). All float32.
__global__ __launch_bounds__(256) void k_erow(const float* E, const float* omega,
                                              const float* alpha,
                                              float* cE, float* LOm, float* LAl) {
    int wid = blockIdx.x * 4 + (threadIdx.x >> 6);
    if (wid >= 258) return;
    int lane = threadIdx.x & 63;
    const float* row = (wid < 256) ? (E + wid * 256)
                      : (wid == 256 ? omega : alpha);
    float4 z = *(const float4*)(row + lane * 4);
    float c = sparsemax_c4(z.x, z.y, z.z, z.w);
    if (wid < 256) {
        if (lane == 0) cE[wid] = c;
    } else {
        float* dst = (wid == 256) ? LOm : LAl;
        *(float4*)(dst + lane * 4) = make_float4(c - z.x, c - z.y, c - z.z, c - z.w);
    }
}

// wid = x*256+q.  Fused: EA[x*256+q] = exp(c_T(T[q,x,:]) + cE[q] - E[q,x]).
// W8 in MFMA fp8 A-fragment order (round-5-verified for the scaled
// 16x16x128 fp8/fp8 contraction — the per-(group,dword,byte) k-map of A
// equals the k-map of the u8b B-fragments):
//   main-kernel wave w (q-tile 16w..16w+15), lane l, uint4 #i2 reads 16 B at
//     x*65536 + w*4096 + i2*1024 + l*16
//   low 8 B = chunk c=2*i2  (k = 32c + 8*(l>>4) + j, j=0..7), high 8 B = 2*i2+1.
// NOTE (round-8 lesson): do NOT port W to fp6/fp4 — the f8f6f4 sub-byte
// register bit-layout is undocumented and a wrong guess is silent garbage.
// NOTE (round-11 lesson): do NOT deepen the register prefetch ring past 2 —
// SIInsertWaitcnts can't see into inline asm, and at ~128-VGPR pressure the
// allocator copies/spills in-flight asm-load destinations (silent stale data).
// R10: block's 16 waves scatter into a 4-KB LDS buffer, then 256 threads
// store contiguous uint4 (measured neutral vs direct scatter; kept).
__global__ __launch_bounds__(1024) void k_trow(const float* T, const float* E,
                                               const float* cE, unsigned char* W8,
                                               float* EA, int writeW) {
    int tid = threadIdx.x;
    int wid = blockIdx.x * 16 + (tid >> 6);
    int lane = tid & 63;
    int x = wid >> 8, q = wid & 255;
    __shared__ __align__(16) unsigned int wbuf[1024];
    const float* row = T + ((size_t)((q << 8) | x) << 8);
    float4 z = *(const float4*)(row + lane * 4);
    float c = sparsemax_c4(z.x, z.y, z.z, z.w);
    if (writeW) {                              // block-uniform
        unsigned int packed = pack4_fp8(__expf(-z.x), __expf(-z.y),
                                        __expf(-z.z), __expf(-z.w));
        int n0 = lane << 2;                // 4 consecutive n share i2,g,half
        // intra-4KB dword index: i2<<8 | g<<6 | (q&15)<<2 | half<<1 | j0>>2
        int lidx = ((n0 >> 6) << 8) | (((n0 >> 3) & 3) << 6)
                 | ((q & 15) << 2) | (((n0 >> 5) & 1) << 1) | ((n0 & 7) >> 2);
        wbuf[lidx] = packed;
        __syncthreads();
        if (tid < 256) {
            size_t base = ((size_t)x << 16) + ((size_t)(q >> 4) << 12);
            *(uint4*)(W8 + base + ((size_t)tid << 4)) =
                *(const uint4*)((const unsigned char*)wbuf + (tid << 4));
        }
    }
    if (lane == 0) EA[wid] = __expf(c + cE[q] - E[(q << 8) + x]);
}

// Prefetch one step's W (4 x dwordx4) + 1 EA float. R12: SGPR-base saddr
// form — x is wave-uniform (readfirstlane), so the slab base lives in an
// SGPR pair computed on the scalar pipe; the VGPR offset is loop-invariant.
// INLINE ASM: volatile loads cannot be sunk (round-4 collapse). Counted
// wait: vmcnt(5) inside STEPX (2-deep ring, 10 outstanding at step top).
#define PF(XS, D0, D1, D2, D3, EAS) do {                                  \
    const unsigned char* bW_ = W8 + ((size_t)(unsigned)(XS) << 16);       \
    const unsigned char* bE_ = (const unsigned char*)EA                   \
                             + ((size_t)(unsigned)(XS) << 10);            \
    asm volatile("global_load_dwordx4 %0, %5, %7\n\t"                     \
                 "global_load_dwordx4 %1, %5, %7 offset:1024\n\t"         \
                 "global_load_dwordx4 %2, %5, %7 offset:2048\n\t"         \
                 "global_load_dwordx4 %3, %5, %7 offset:3072\n\t"         \
                 "global_load_dword   %4, %6, %8"                         \
                 : "=&v"(D0), "=&v"(D1), "=&v"(D2), "=&v"(D3), "=&v"(EAS) \
                 : "v"(voffW), "v"(voffE), "s"(bW_), "s"(bE_));           \
} while (0)

// One recursion step. Exact for any positive wave-uniform scale (accounted
// in LM). Rescale is PARITY (1-step-stale) — log-level recursion
// m_{t+1} = m_t - m_{t-1} + c has |roots| = 1 exactly (bounded oscillation).
// Deeper staleness is UNSTABLE (|z|=1.15, round-3 failure) — do not deepen.
// Order (r9 hoist): B ds_reads + rs2 read FIRST — their ~120cyc LDS latency
// overlaps the W vmcnt wait — then vmcnt(5) + sched_barrier (stops MFMA
// hoisting past the wait, rule #18), then the 2 scaled MFMAs.
#if HW_MXF8
#define STEPX(XC, W0, W1_, W2_, W3_, EAS) do {                           \
    const u32x4* bv_ = (const u32x4*)u8b[pb];                            \
    u32x4 B0 = bv_[(g << 2) + 0];                                        \
    u32x4 B1 = bv_[(g << 2) + 1];                                        \
    u32x4 B2 = bv_[(g << 2) + 2];                                        \
    u32x4 B3 = bv_[(g << 2) + 3];                                        \
    float rr_ = rs2[pb];                                                 \
    asm volatile("s_waitcnt vmcnt(5)" ::: "memory");                     \
    __builtin_amdgcn_sched_barrier(0);                                   \
    if ((XC) != 0) {                                                     \
        f32x4 ac0 = {0.f, 0.f, 0.f, 0.f}, ac1 = {0.f, 0.f, 0.f, 0.f};    \
        ac0 = __builtin_amdgcn_mfma_scale_f32_16x16x128_f8f6f4(          \
                pk8(W0, W1_), pk8(B0, B1), ac0, 0, 0,                    \
                0, 0x7F7F7F7F, 0, 0x7F7F7F7F);                           \
        ac1 = __builtin_amdgcn_mfma_scale_f32_16x16x128_f8f6f4(          \
                pk8(W2_, W3_), pk8(B2, B3), ac1, 0, 0,                   \
                0, 0x7F7F7F7F, 0, 0x7F7F7F7F);                           \
        f32x4 sv = ac0 + ac1;   /* all 16 cols identical; rows 4g..4g+3 */ \
        float svr = (r_ == 0) ? sv.x : (r_ == 1) ? sv.y                  \
                  : (r_ == 2) ? sv.z : sv.w;                             \
        if (isw) {                                                       \
            float nu = (EAS) * svr * rr_;                                \
            u_lastS = nu;                                                \
            u8c[((pb ^ 1) << 8) + wbyte] = fp8_1(nu);                    \
        }                                                                \
        if (tid == 0) { rs2[pb ^ 1] = 0.0625f / fmaxf(sv.x, 1e-30f);     \
                        LM -= __logf(rr_); }                             \
    } else {                                                             \
        if (isw) u8c[((pb ^ 1) << 8) + wbyte] = u8c[(pb << 8) + wbyte];  \
        if (tid == 0) rs2[pb ^ 1] = rs2[pb];                             \
    }                                                                    \
    pb ^= 1;                                                             \
    sync_lds();                                                          \
} while (0)
#else
#define STEPX(XC, W0, W1_, W2_, W3_, EAS) do {                           \
    const u32x4* bv_ = (const u32x4*)u8b[pb];                            \
    u32x4 B0 = bv_[(g << 2) + 0];                                        \
    u32x4 B1 = bv_[(g << 2) + 1];                                        \
    u32x4 B2 = bv_[(g << 2) + 2];                                        \
    u32x4 B3 = bv_[(g << 2) + 3];                                        \
    float rr_ = rs2[pb];                                                 \
    asm volatile("s_waitcnt vmcnt(5)" ::: "memory");                     \
    __builtin_amdgcn_sched_barrier(0);                                   \
    if ((XC) != 0) {                                                     \
        f32x4 ac0 = {0.f, 0.f, 0.f, 0.f}, ac1 = {0.f, 0.f, 0.f, 0.f};    \
        ac0 = __builtin_amdgcn_mfma_f32_16x16x32_fp8_fp8(mk64(W0[0], W0[1]),   mk64(B0[0], B0[1]), ac0, 0, 0, 0); \
        ac1 = __builtin_amdgcn_mfma_f32_16x16x32_fp8_fp8(mk64(W0[2], W0[3]),   mk64(B0[2], B0[3]), ac1, 0, 0, 0); \
        ac0 = __builtin_amdgcn_mfma_f32_16x16x32_fp8_fp8(mk64(W1_[0], W1_[1]), mk64(B1[0], B1[1]), ac0, 0, 0, 0); \
        ac1 = __builtin_amdgcn_mfma_f32_16x16x32_fp8_fp8(mk64(W1_[2], W1_[3]), mk64(B1[2], B1[3]), ac1, 0, 0, 0); \
        ac0 = __builtin_amdgcn_mfma_f32_16x16x32_fp8_fp8(mk64(W2_[0], W2_[1]), mk64(B2[0], B2[1]), ac0, 0, 0, 0); \
        ac1 = __builtin_amdgcn_mfma_f32_16x16x32_fp8_fp8(mk64(W2_[2], W2_[3]), mk64(B2[2], B2[3]), ac1, 0, 0, 0); \
        ac0 = __builtin_amdgcn_mfma_f32_16x16x32_fp8_fp8(mk64(W3_[0], W3_[1]), mk64(B3[0], B3[1]), ac0, 0, 0, 0); \
        ac1 = __builtin_amdgcn_mfma_f32_16x16x32_fp8_fp8(mk64(W3_[2], W3_[3]), mk64(B3[2], B3[3]), ac1, 0, 0, 0); \
        f32x4 sv = ac0 + ac1;                                            \
        float svr = (r_ == 0) ? sv.x : (r_ == 1) ? sv.y                  \
                  : (r_ == 2) ? sv.z : sv.w;                             \
        if (isw) {                                                       \
            float nu = (EAS) * svr * rr_;                                \
            u_lastS = nu;                                                \
            u8c[((pb ^ 1) << 8) + wbyte] = fp8_1(nu);                    \
        }                                                                \
        if (tid == 0) { rs2[pb ^ 1] = 0.0625f / fmaxf(sv.x, 1e-30f);     \
                        LM -= __logf(rr_); }                             \
    } else {                                                             \
        if (isw) u8c[((pb ^ 1) << 8) + wbyte] = u8c[(pb << 8) + wbyte];  \
        if (tid == 0) rs2[pb ^ 1] = rs2[pb];                             \
    }                                                                    \
    pb ^= 1;                                                             \
    sync_lds();                                                          \
} while (0)
#endif

// ---- main recursion: 16 waves, wave w owns q-tile [16w,16w+16).
// Per step: 2 x mfma_scale_f32_16x16x128 (fp8 x fp8, K=256, scale=1.0).
// W + EA register-prefetched TWO steps ahead via volatile-asm saddr loads
// (SGPR slab base, invariant VGPR offset); vmcnt(5) inside each step after
// the hoisted B ds_reads. At its structural floor (r13): step ~1540 cyc ≈
// max(TCP fill 64KB/step ~1024 cyc, serial barrier+LDS+MFMA chain). ----
__global__ __launch_bounds__(1024) void k_main_fast(const int* xs, const unsigned char* W8,
                                                    const float* EA, const float* LOm,
                                                    const float* LAl, float* per_seq) {
    int b = blockIdx.x, tid = threadIdx.x;
    int lane = tid & 63, w = tid >> 6, g = lane >> 4;
    int r_ = lane & 3;
    __shared__ int xsh[LDIM];
    __shared__ float red[4];
    __shared__ float rs2[2];
    __shared__ float lm_sh;
    __shared__ __align__(16) unsigned int u8b[2][64];   // fp8 u, frag order
    __shared__ __align__(16) float u_f[256];            // final u (f32)
    unsigned char* u8c = (unsigned char*)u8b;
    if (tid < LDIM) xsh[tid] = xs[b * LDIM + tid];
    if (tid < 64) {
        // dword d covers n = 32c + 8gg + j0 .. +3
        int gg = tid >> 4, cch = (tid >> 1) & 7, j0 = (tid & 1) << 2;
        int n0 = (cch << 5) + (gg << 3) + j0;
        float4 lv = *(const float4*)(LOm + n0);
        u8b[0][tid] = pack4_fp8(__expf(lv.x), __expf(lv.y), __expf(lv.z), __expf(lv.w));
    }
    if (tid < 2) rs2[tid] = 0.0625f / 256.0f;
    __syncthreads();

    float LM = 0.f;
    int pb = 0;
    int isw = ((lane & 15) < 4);               // 4 writer lanes per 16-lane col group
    int q0 = (w << 4) + (g << 2);              // this lane's 4-row base
    int wdw = (((q0 >> 3) & 3) << 4) + ((q0 >> 5) << 1) + ((q0 & 7) >> 2);
    int wbyte = (wdw << 2) + r_;               // byte slot of row q0+r_ in u8b
    float u_lastS = 1.f;
    int voffW = (w << 12) + (lane << 4);       // loop-invariant W lane offset
    int voffE = (q0 + r_) << 2;                // loop-invariant EA lane offset

    u32x4 A0, A1, A2, A3, Bb0, Bb1, Bb2, Bb3;
    float eA, eB;
    int x0 = __builtin_amdgcn_readfirstlane(xsh[511]);
    int x1 = __builtin_amdgcn_readfirstlane(xsh[510]);
    PF(x0, A0, A1, A2, A3, eA);
    PF(x1, Bb0, Bb1, Bb2, Bb3, eB);
    for (int it = 0; it < 256; ++it) {
        int pf = 509 - (it << 1);
        int y0 = (pf >= 0) ? __builtin_amdgcn_readfirstlane(xsh[pf])     : 0;
        int y1 = (pf >= 1) ? __builtin_amdgcn_readfirstlane(xsh[pf - 1]) : 0;
        STEPX(x0, A0, A1, A2, A3, eA);     PF(y0, A0, A1, A2, A3, eA);
        STEPX(x1, Bb0, Bb1, Bb2, Bb3, eB); PF(y1, Bb0, Bb1, Bb2, Bb3, eB);
        x0 = y0; x1 = y1;
    }
    asm volatile("s_waitcnt vmcnt(0)" ::: "memory");   // drain dangling loads

    // per_seq[b] = LM + lse_q(LAl[q] + log u[q]); u_lastS is from the last
    // non-skip step (f32, pre-quantization).
    if (isw) u_f[q0 + r_] = u_lastS;
    if (tid == 0) lm_sh = LM;
    __syncthreads();
    float v = -3.0e38f;
    if (tid < 256) v = LAl[tid] + __logf(fmaxf(u_f[tid], 1e-37f));
    float m2 = wred_max(v);
    if (tid < 256 && (tid & 63) == 0) red[tid >> 6] = m2;
    __syncthreads();
    m2 = fmaxf(fmaxf(red[0], red[1]), fmaxf(red[2], red[3]));
    float e = (tid < 256) ? __expf(v - m2) : 0.f;
    float es = wred_add(e);
    __syncthreads();
    if (tid < 256 && (tid & 63) == 0) red[tid >> 6] = es;
    __syncthreads();
    if (tid == 0) per_seq[b] = lm_sh + m2 + __logf(red[0] + red[1] + red[2] + red[3]);
}

// ---- fallback (small ws): read T (f32) directly, exp on the fly.
//      EA holds exp(A), so take logf of it. ----
__global__ __launch_bounds__(256) void k_main_med(const int* xs, const float* T,
                                                  const float* A, const float* LOm,
                                                  const float* LAl, float* per_seq) {
    int b = blockIdx.x, q = threadIdx.x;
    __shared__ int xsh[LDIM];
    __shared__ float red[4];
    __shared__ __align__(16) float u_f[256];
    for (int i = q; i < LDIM; i += 256) xsh[i] = xs[b * LDIM + i];
    float c = LOm[q];
    __syncthreads();
    for (int t = LDIM - 1; t >= 0; --t) {
        int x = xsh[t];
        if (x != 0) {
            float m = wred_max(c);
            if ((q & 63) == 0) red[q >> 6] = m;
            __syncthreads();
            m = fmaxf(fmaxf(red[0], red[1]), fmaxf(red[2], red[3]));
            u_f[q] = __expf(c - m);
            __syncthreads();
            const float* Tp = T + (((size_t)(q << 8) + (size_t)x) << 8);
            float acc = 0.f;
            #pragma unroll 4
            for (int i = 0; i < 32; ++i) {
                float4 ta = *(const float4*)(Tp + (i << 3));
                float4 tb = *(const float4*)(Tp + (i << 3) + 4);
                float4 ua = *(const float4*)(u_f + (i << 3));
                float4 ub = *(const float4*)(u_f + (i << 3) + 4);
                acc = fmaf(__expf(-ta.x), ua.x, acc);
                acc = fmaf(__expf(-ta.y), ua.y, acc);
                acc = fmaf(__expf(-ta.z), ua.z, acc);
                acc = fmaf(__expf(-ta.w), ua.w, acc);
                acc = fmaf(__expf(-tb.x), ub.x, acc);
                acc = fmaf(__expf(-tb.y), ub.y, acc);
                acc = fmaf(__expf(-tb.z), ub.z, acc);
                acc = fmaf(__expf(-tb.w), ub.w, acc);
            }
            acc = fmaxf(acc, 1e-30f);
            c = __logf(A[(x << 8) + q]) + m + __logf(acc);
        }
    }
    float v = LAl[q] + c;
    float m2 = wred_max(v);
    if ((q & 63) == 0) red[q >> 6] = m2;
    __syncthreads();
    m2 = fmaxf(fmaxf(red[0], red[1]), fmaxf(red[2], red[3]));
    float es = wred_add(__expf(v - m2));
    __syncthreads();
    if ((q & 63) == 0) red[q >> 6] = es;
    __syncthreads();
    if (q == 0) per_seq[b] = m2 + __logf(red[0] + red[1] + red[2] + red[3]);
}

__global__ __launch_bounds__(64) void k_final(const float* per_seq, float* out) {
    if (threadIdx.x == 0) {
        float s = 0.f;
        for (int i = 0; i < BDIM; ++i) s += per_seq[i];
        out[0] = s;
    }
}

extern "C" void kernel_launch(void* const* d_in, const int* in_sizes, int n_in,
                              void* d_out, int out_size, void* d_ws, size_t ws_size,
                              hipStream_t stream) {
    const int* xs = nullptr;
    const float *alpha = nullptr, *omega = nullptr, *E = nullptr, *T = nullptr;
    int seen256 = 0;
    for (int i = 0; i < n_in; ++i) {
        int s = in_sizes[i];
        if      (s == 16777216) T  = (const float*)d_in[i];
        else if (s == 65536)    E  = (const float*)d_in[i];
        else if (s == 8192)     xs = (const int*)d_in[i];
        else if (s == 256) { if (seen256++ == 0) alpha = (const float*)d_in[i];
                             else                omega = (const float*)d_in[i]; }
    }

    char* ws = (char*)d_ws;
    float* EA       = (float*)(ws + WS_A);
    float* cE       = (float*)(ws + WS_CE);
    float* LOm      = (float*)(ws + WS_LOM);
    float* LAl      = (float*)(ws + WS_LAL);
    float* per_seq  = (float*)(ws + WS_PS);
    unsigned char* W8 = (unsigned char*)(ws + WS_W);
    int fast = (ws_size >= WS_FAST_BYTES) ? 1 : 0;

    k_erow<<<65, 256, 0, stream>>>(E, omega, alpha, cE, LOm, LAl);
    k_trow<<<4096, 1024, 0, stream>>>(T, E, cE, W8, EA, fast);
    if (fast) k_main_fast<<<BDIM, 1024, 0, stream>>>(xs, W8, EA, LOm, LAl, per_seq);
    else      k_main_med <<<BDIM, 256, 0, stream>>>(xs, T, EA, LOm, LAl, per_seq);
    k_final<<<1, 64, 0, stream>>>(per_seq, (float*)d_out);
}

// Round 16
// 446.910 us; speedup vs baseline: 1.0734x; 1.0020x over previous
//
#include <hip/hip_runtime.h>
#include <hip/hip_fp16.h>

#define LDIM 512
#define BDIM 16

// ws layout: small arrays first so the fallback path works with small ws.
#define WS_A    0u          // 262144 B  (float EA[256*256], EA[x*256+q] = exp(A))
#define WS_CE   262144u     // 1024 B
#define WS_LOM  263168u     // 1024 B
#define WS_LAL  264192u     // 1024 B
#define WS_PS   265216u     // 64 B
#define WS_W    270336u     // 16777216 B (fp8 W, MFMA fragment layout), 16B aligned
#define WS_FAST_BYTES (270336ull + 16777216ull)

typedef float f32x4 __attribute__((ext_vector_type(4)));
typedef int   i32x8 __attribute__((ext_vector_type(8)));
typedef unsigned int u32x4 __attribute__((ext_vector_type(4)));

__device__ __forceinline__ float wred_add(float v) {
    #pragma unroll
    for (int off = 32; off; off >>= 1) v += __shfl_xor(v, off);
    return v;
}
__device__ __forceinline__ float wred_max(float v) {
    #pragma unroll
    for (int off = 32; off; off >>= 1) v = fmaxf(v, __shfl_xor(v, off));
    return v;
}

// R15: wave64 float sum on the VALU pipe via DPP (0 DS ops, ~4cyc dependent
// latency vs ~35cyc ds_swizzle). Canonical GCN sequence: after the 6 adds,
// lane 63 holds the full sum; readlane broadcasts it. s_nop 1 between
// dependent DPP ops (VALU-write -> DPP-read hazard; the compiler cannot see
// inside the asm block, so the wait states are manual — r11-class lesson).
__device__ __forceinline__ float dpp_sum(float v) {
    float r = v;
    asm volatile(
        "s_nop 1\n\t"
        "v_add_f32 %0, %0, %0 row_shr:1 row_mask:0xf bank_mask:0xf bound_ctrl:0\n\t"
        "s_nop 1\n\t"
        "v_add_f32 %0, %0, %0 row_shr:2 row_mask:0xf bank_mask:0xf bound_ctrl:0\n\t"
        "s_nop 1\n\t"
        "v_add_f32 %0, %0, %0 row_shr:4 row_mask:0xf bank_mask:0xe\n\t"
        "s_nop 1\n\t"
        "v_add_f32 %0, %0, %0 row_shr:8 row_mask:0xf bank_mask:0xc\n\t"
        "s_nop 1\n\t"
        "v_add_f32 %0, %0, %0 row_bcast:15 row_mask:0xa bank_mask:0xf\n\t"
        "s_nop 1\n\t"
        "v_add_f32 %0, %0, %0 row_bcast:31 row_mask:0xc bank_mask:0xf\n\t"
        "s_nop 1"
        : "+v"(r));
    return __int_as_float(__builtin_amdgcn_readlane(__float_as_int(r), 63));
}

#if __has_builtin(__builtin_amdgcn_cvt_pk_f32_fp8) && __has_builtin(__builtin_amdgcn_cvt_pk_fp8_f32)
#define HW_FP8 1
#else
#define HW_FP8 0
#endif
#if __has_builtin(__builtin_amdgcn_mfma_scale_f32_16x16x128_f8f6f4)
#define HW_MXF8 1
#else
#define HW_MXF8 0
#endif

// Fallback software e4m3fn (normals only).
__device__ __forceinline__ unsigned int sw_fp8_enc(float a) {
    union { float f; unsigned int u; } x; x.f = a;
    unsigned int u = x.u + 0x80000u;               // round at mantissa bit 19
    return (((u >> 23) & 0xffu) - 120u) * 8u + ((u >> 20) & 7u);
}
__device__ __forceinline__ unsigned int pack4_fp8(float a, float b, float c, float d) {
#if HW_FP8
    int v = 0;
    v = __builtin_amdgcn_cvt_pk_fp8_f32(a, b, v, false);   // bytes 0,1
    v = __builtin_amdgcn_cvt_pk_fp8_f32(c, d, v, true);    // bytes 2,3
    return (unsigned int)v;
#else
    return sw_fp8_enc(a) | (sw_fp8_enc(b) << 8) | (sw_fp8_enc(c) << 16) | (sw_fp8_enc(d) << 24);
#endif
}
__device__ __forceinline__ unsigned char fp8_1(float a) {
#if HW_FP8
    return (unsigned char)(__builtin_amdgcn_cvt_pk_fp8_f32(a, a, 0, false) & 0xff);
#else
    return (unsigned char)sw_fp8_enc(a);
#endif
}

__device__ __forceinline__ long mk64(unsigned int lo, unsigned int hi) {
    return (long)(((unsigned long long)hi << 32) | (unsigned long long)lo);
}
__device__ __forceinline__ i32x8 pk8(u32x4 a, u32x4 b) {
    i32x8 r;
    r[0] = (int)a[0]; r[1] = (int)a[1]; r[2] = (int)a[2]; r[3] = (int)a[3];
    r[4] = (int)b[0]; r[5] = (int)b[1]; r[6] = (int)b[2]; r[7] = (int)b[3];
    return r;
}

// Raw barrier: only drains LDS (lgkmcnt). Global prefetch loads stay in
// flight across it. sched_barrier(0) fences pin compile-time ordering.
__device__ __forceinline__ void sync_lds() {
    asm volatile("s_waitcnt lgkmcnt(0)" ::: "memory");
    __builtin_amdgcn_sched_barrier(0);
    __builtin_amdgcn_s_barrier();
    __builtin_amdgcn_sched_barrier(0);
    asm volatile("" ::: "memory");
}

// Michelot exact sparsemax over a wave's 256 values (4 per lane).
// Returns c = <z,p*> - 0.5||p*||^2 + 0.5 (wave-uniform).
// R14: support-count via ballot+popcount (0 DS ops). R15: float sums via
// DPP on the VALU pipe (0 DS ops) — the sparsemax loop issues zero
// LDS-pipe operations.
__device__ float sparsemax_c4(float z0, float z1, float z2, float z3) {
    float ssum = dpp_sum(z0 + z1 + z2 + z3);
    float tau = (ssum - 1.0f) * (1.0f / 256.0f);
    int kprev = 256;
    for (int it = 0; it < 64; ++it) {
        float s = 0.f;
        if (z0 > tau) s += z0;
        if (z1 > tau) s += z1;
        if (z2 > tau) s += z2;
        if (z3 > tau) s += z3;
        s = dpp_sum(s);
        int k = __popcll(__ballot(z0 > tau)) + __popcll(__ballot(z1 > tau))
              + __popcll(__ballot(z2 > tau)) + __popcll(__ballot(z3 > tau));
        tau = (s - 1.0f) / (float)k;       // k >= 1 invariant (max > tau)
        if (k == kprev) break;
        kprev = k;
    }
    float cs = 0.f, t2 = tau * tau;
    if (z0 > tau) cs += z0 * z0 - t2;
    if (z1 > tau) cs += z1 * z1 - t2;
    if (z2 > tau) cs += z2 * z2 - t2;
    if (z3 > tau) cs += z3 * z3 - t2;
    cs = dpp_sum(cs);
    return 0.5f * cs + 0.5f;
}

// Rows of E (256) + omega (1) + alpha (1). All float32.
__global__ __launch_bounds__(256) void k_erow(const float* E, const float* omega,
                                              const float* alpha,
                                              float* cE, float* LOm, float* LAl) {
    int wid = blockIdx.x * 4 + (threadIdx.x >> 6);
    if (wid >= 258) return;
    int lane = threadIdx.x & 63;
    const float* row = (wid < 256) ? (E + wid * 256)
                      : (wid == 256 ? omega : alpha);
    float4 z = *(const float4*)(row + lane * 4);
    float c = sparsemax_c4(z.x, z.y, z.z, z.w);
    if (wid < 256) {
        if (lane == 0) cE[wid] = c;
    } else {
        float* dst = (wid == 256) ? LOm : LAl;
        *(float4*)(dst + lane * 4) = make_float4(c - z.x, c - z.y, c - z.z, c - z.w);
    }
}

// wid = x*256+q.  Fused: EA[x*256+q] = exp(c_T(T[q,x,:]) + cE[q] - E[q,x]).
// W8 in MFMA fp8 A-fragment order (round-5-verified for the scaled
// 16x16x128 fp8/fp8 contraction — the per-(group,dword,byte) k-map of A
// equals the k-map of the u8b B-fragments):
//   main-kernel wave w (q-tile 16w..16w+15), lane l, uint4 #i2 reads 16 B at
//     x*65536 + w*4096 + i2*1024 + l*16
//   low 8 B = chunk c=2*i2  (k = 32c + 8*(l>>4) + j, j=0..7), high 8 B = 2*i2+1.
// NOTE (round-8 lesson): do NOT port W to fp6/fp4 — the f8f6f4 sub-byte
// register bit-layout is undocumented and a wrong guess is silent garbage.
// NOTE (round-11 lesson): do NOT deepen the register prefetch ring past 2 —
// SIInsertWaitcnts can't see into inline asm, and at ~128-VGPR pressure the
// allocator copies/spills in-flight asm-load destinations (silent stale data).
// R16: k_trow is latency-bound (r14/r15: removing ALL hot-loop DS ops only
// recovered 32 of ~105 us; throughput ~3.9k cyc/row vs ~700 cyc VALU issue).
// __launch_bounds__(1024, 8) requests 8 waves/EU (= 2 blocks/CU), capping
// VGPR at 64 to double resident waves and the latency overlap.
__global__ __launch_bounds__(1024, 8) void k_trow(const float* T, const float* E,
                                                  const float* cE, unsigned char* W8,
                                                  float* EA, int writeW) {
    int tid = threadIdx.x;
    int wid = blockIdx.x * 16 + (tid >> 6);
    int lane = tid & 63;
    int x = wid >> 8, q = wid & 255;
    __shared__ __align__(16) unsigned int wbuf[1024];
    const float* row = T + ((size_t)((q << 8) | x) << 8);
    float4 z = *(const float4*)(row + lane * 4);
    float c = sparsemax_c4(z.x, z.y, z.z, z.w);
    if (writeW) {                              // block-uniform
        unsigned int packed = pack4_fp8(__expf(-z.x), __expf(-z.y),
                                        __expf(-z.z), __expf(-z.w));
        int n0 = lane << 2;                // 4 consecutive n share i2,g,half
        // intra-4KB dword index: i2<<8 | g<<6 | (q&15)<<2 | half<<1 | j0>>2
        int lidx = ((n0 >> 6) << 8) | (((n0 >> 3) & 3) << 6)
                 | ((q & 15) << 2) | (((n0 >> 5) & 1) << 1) | ((n0 & 7) >> 2);
        wbuf[lidx] = packed;
        __syncthreads();
        if (tid < 256) {
            size_t base = ((size_t)x << 16) + ((size_t)(q >> 4) << 12);
            *(uint4*)(W8 + base + ((size_t)tid << 4)) =
                *(const uint4*)((const unsigned char*)wbuf + (tid << 4));
        }
    }
    if (lane == 0) EA[wid] = __expf(c + cE[q] - E[(q << 8) + x]);
}

// Prefetch one step's W (4 x dwordx4) + 1 EA float. R12: SGPR-base saddr
// form — x is wave-uniform (readfirstlane), so the slab base lives in an
// SGPR pair computed on the scalar pipe; the VGPR offset is loop-invariant.
// INLINE ASM: volatile loads cannot be sunk (round-4 collapse). Counted
// wait: vmcnt(5) inside STEPX (2-deep ring, 10 outstanding at step top).
#define PF(XS, D0, D1, D2, D3, EAS) do {                                  \
    const unsigned char* bW_ = W8 + ((size_t)(unsigned)(XS) << 16);       \
    const unsigned char* bE_ = (const unsigned char*)EA                   \
                             + ((size_t)(unsigned)(XS) << 10);            \
    asm volatile("global_load_dwordx4 %0, %5, %7\n\t"                     \
                 "global_load_dwordx4 %1, %5, %7 offset:1024\n\t"         \
                 "global_load_dwordx4 %2, %5, %7 offset:2048\n\t"         \
                 "global_load_dwordx4 %3, %5, %7 offset:3072\n\t"         \
                 "global_load_dword   %4, %6, %8"                         \
                 : "=&v"(D0), "=&v"(D1), "=&v"(D2), "=&v"(D3), "=&v"(EAS) \
                 : "v"(voffW), "v"(voffE), "s"(bW_), "s"(bE_));           \
} while (0)

// One recursion step. Exact for any positive wave-uniform scale (accounted
// in LM). Rescale is PARITY (1-step-stale) — log-level recursion
// m_{t+1} = m_t - m_{t-1} + c has |roots| = 1 exactly (bounded oscillation).
// Deeper staleness is UNSTABLE (|z|=1.15, round-3 failure) — do not deepen.
// Order (r9 hoist): B ds_reads + rs2 read FIRST — their ~120cyc LDS latency
// overlaps the W vmcnt wait — then vmcnt(5) + sched_barrier (stops MFMA
// hoisting past the wait, rule #18), then the 2 scaled MFMAs.
#if HW_MXF8
#define STEPX(XC, W0, W1_, W2_, W3_, EAS) do {                           \
    const u32x4* bv_ = (const u32x4*)u8b[pb];                            \
    u32x4 B0 = bv_[(g << 2) + 0];                                        \
    u32x4 B1 = bv_[(g << 2) + 1];                                        \
    u32x4 B2 = bv_[(g << 2) + 2];                                        \
    u32x4 B3 = bv_[(g << 2) + 3];                                        \
    float rr_ = rs2[pb];                                                 \
    asm volatile("s_waitcnt vmcnt(5)" ::: "memory");                     \
    __builtin_amdgcn_sched_barrier(0);                                   \
    if ((XC) != 0) {                                                     \
        f32x4 ac0 = {0.f, 0.f, 0.f, 0.f}, ac1 = {0.f, 0.f, 0.f, 0.f};    \
        ac0 = __builtin_amdgcn_mfma_scale_f32_16x16x128_f8f6f4(          \
                pk8(W0, W1_), pk8(B0, B1), ac0, 0, 0,                    \
                0, 0x7F7F7F7F, 0, 0x7F7F7F7F);                           \
        ac1 = __builtin_amdgcn_mfma_scale_f32_16x16x128_f8f6f4(          \
                pk8(W2_, W3_), pk8(B2, B3), ac1, 0, 0,                   \
                0, 0x7F7F7F7F, 0, 0x7F7F7F7F);                           \
        f32x4 sv = ac0 + ac1;   /* all 16 cols identical; rows 4g..4g+3 */ \
        float svr = (r_ == 0) ? sv.x : (r_ == 1) ? sv.y                  \
                  : (r_ == 2) ? sv.z : sv.w;                             \
        if (isw) {                                                       \
            float nu = (EAS) * svr * rr_;                                \
            u_lastS = nu;                                                \
            u8c[((pb ^ 1) << 8) + wbyte] = fp8_1(nu);                    \
        }                                                                \
        if (tid == 0) { rs2[pb ^ 1] = 0.0625f / fmaxf(sv.x, 1e-30f);     \
                        LM -= __logf(rr_); }                             \
    } else {                                                             \
        if (isw) u8c[((pb ^ 1) << 8) + wbyte] = u8c[(pb << 8) + wbyte];  \
        if (tid == 0) rs2[pb ^ 1] = rs2[pb];                             \
    }                                                                    \
    pb ^= 1;                                                             \
    sync_lds();                                                          \
} while (0)
#else
#define STEPX(XC, W0, W1_, W2_, W3_, EAS) do {                           \
    const u32x4* bv_ = (const u32x4*)u8b[pb];                            \
    u32x4 B0 = bv_[(g << 2) + 0];                                        \
    u32x4 B1 = bv_[(g << 2) + 1];                                        \
    u32x4 B2 = bv_[(g << 2) + 2];                                        \
    u32x4 B3 = bv_[(g << 2) + 3];                                        \
    float rr_ = rs2[pb];                                                 \
    asm volatile("s_waitcnt vmcnt(5)" ::: "memory");                     \
    __builtin_amdgcn_sched_barrier(0);                                   \
    if ((XC) != 0) {                                                     \
        f32x4 ac0 = {0.f, 0.f, 0.f, 0.f}, ac1 = {0.f, 0.f, 0.f, 0.f};    \
        ac0 = __builtin_amdgcn_mfma_f32_16x16x32_fp8_fp8(mk64(W0[0], W0[1]),   mk64(B0[0], B0[1]), ac0, 0, 0, 0); \
        ac1 = __builtin_amdgcn_mfma_f32_16x16x32_fp8_fp8(mk64(W0[2], W0[3]),   mk64(B0[2], B0[3]), ac1, 0, 0, 0); \
        ac0 = __builtin_amdgcn_mfma_f32_16x16x32_fp8_fp8(mk64(W1_[0], W1_[1]), mk64(B1[0], B1[1]), ac0, 0, 0, 0); \
        ac1 = __builtin_amdgcn_mfma_f32_16x16x32_fp8_fp8(mk64(W1_[2], W1_[3]), mk64(B1[2], B1[3]), ac1, 0, 0, 0); \
        ac0 = __builtin_amdgcn_mfma_f32_16x16x32_fp8_fp8(mk64(W2_[0], W2_[1]), mk64(B2[0], B2[1]), ac0, 0, 0, 0); \
        ac1 = __builtin_amdgcn_mfma_f32_16x16x32_fp8_fp8(mk64(W2_[2], W2_[3]), mk64(B2[2], B2[3]), ac1, 0, 0, 0); \
        ac0 = __builtin_amdgcn_mfma_f32_16x16x32_fp8_fp8(mk64(W3_[0], W3_[1]), mk64(B3[0], B3[1]), ac0, 0, 0, 0); \
        ac1 = __builtin_amdgcn_mfma_f32_16x16x32_fp8_fp8(mk64(W3_[2], W3_[3]), mk64(B3[2], B3[3]), ac1, 0, 0, 0); \
        f32x4 sv = ac0 + ac1;                                            \
        float svr = (r_ == 0) ? sv.x : (r_ == 1) ? sv.y                  \
                  : (r_ == 2) ? sv.z : sv.w;                             \
        if (isw) {                                                       \
            float nu = (EAS) * svr * rr_;                                \
            u_lastS = nu;                                                \
            u8c[((pb ^ 1) << 8) + wbyte] = fp8_1(nu);                    \
        }                                                                \
        if (tid == 0) { rs2[pb ^ 1] = 0.0625f / fmaxf(sv.x, 1e-30f);     \
                        LM -= __logf(rr_); }                             \
    } else {                                                             \
        if (isw) u8c[((pb ^ 1) << 8) + wbyte] = u8c[(pb << 8) + wbyte];  \
        if (tid == 0) rs2[pb ^ 1] = rs2[pb];                             \
    }                                                                    \
    pb ^= 1;                                                             \
    sync_lds();                                                          \
} while (0)
#endif

// ---- main recursion: 16 waves, wave w owns q-tile [16w,16w+16).
// Per step: 2 x mfma_scale_f32_16x16x128 (fp8 x fp8, K=256, scale=1.0).
// W + EA register-prefetched TWO steps ahead via volatile-asm saddr loads
// (SGPR slab base, invariant VGPR offset); vmcnt(5) inside each step after
// the hoisted B ds_reads. At its structural floor (r13): step ~1540 cyc ≈
// max(TCP fill 64KB/step ~1024 cyc, serial barrier+LDS+MFMA chain). ----
__global__ __launch_bounds__(1024) void k_main_fast(const int* xs, const unsigned char* W8,
                                                    const float* EA, const float* LOm,
                                                    const float* LAl, float* per_seq) {
    int b = blockIdx.x, tid = threadIdx.x;
    int lane = tid & 63, w = tid >> 6, g = lane >> 4;
    int r_ = lane & 3;
    __shared__ int xsh[LDIM];
    __shared__ float red[4];
    __shared__ float rs2[2];
    __shared__ float lm_sh;
    __shared__ __align__(16) unsigned int u8b[2][64];   // fp8 u, frag order
    __shared__ __align__(16) float u_f[256];            // final u (f32)
    unsigned char* u8c = (unsigned char*)u8b;
    if (tid < LDIM) xsh[tid] = xs[b * LDIM + tid];
    if (tid < 64) {
        // dword d covers n = 32c + 8gg + j0 .. +3
        int gg = tid >> 4, cch = (tid >> 1) & 7, j0 = (tid & 1) << 2;
        int n0 = (cch << 5) + (gg << 3) + j0;
        float4 lv = *(const float4*)(LOm + n0);
        u8b[0][tid] = pack4_fp8(__expf(lv.x), __expf(lv.y), __expf(lv.z), __expf(lv.w));
    }
    if (tid < 2) rs2[tid] = 0.0625f / 256.0f;
    __syncthreads();

    float LM = 0.f;
    int pb = 0;
    int isw = ((lane & 15) < 4);               // 4 writer lanes per 16-lane col group
    int q0 = (w << 4) + (g << 2);              // this lane's 4-row base
    int wdw = (((q0 >> 3) & 3) << 4) + ((q0 >> 5) << 1) + ((q0 & 7) >> 2);
    int wbyte = (wdw << 2) + r_;               // byte slot of row q0+r_ in u8b
    float u_lastS = 1.f;
    int voffW = (w << 12) + (lane << 4);       // loop-invariant W lane offset
    int voffE = (q0 + r_) << 2;                // loop-invariant EA lane offset

    u32x4 A0, A1, A2, A3, Bb0, Bb1, Bb2, Bb3;
    float eA, eB;
    int x0 = __builtin_amdgcn_readfirstlane(xsh[511]);
    int x1 = __builtin_amdgcn_readfirstlane(xsh[510]);
    PF(x0, A0, A1, A2, A3, eA);
    PF(x1, Bb0, Bb1, Bb2, Bb3, eB);
    for (int it = 0; it < 256; ++it) {
        int pf = 509 - (it << 1);
        int y0 = (pf >= 0) ? __builtin_amdgcn_readfirstlane(xsh[pf])     : 0;
        int y1 = (pf >= 1) ? __builtin_amdgcn_readfirstlane(xsh[pf - 1]) : 0;
        STEPX(x0, A0, A1, A2, A3, eA);     PF(y0, A0, A1, A2, A3, eA);
        STEPX(x1, Bb0, Bb1, Bb2, Bb3, eB); PF(y1, Bb0, Bb1, Bb2, Bb3, eB);
        x0 = y0; x1 = y1;
    }
    asm volatile("s_waitcnt vmcnt(0)" ::: "memory");   // drain dangling loads

    // per_seq[b] = LM + lse_q(LAl[q] + log u[q]); u_lastS is from the last
    // non-skip step (f32, pre-quantization).
    if (isw) u_f[q0 + r_] = u_lastS;
    if (tid == 0) lm_sh = LM;
    __syncthreads();
    float v = -3.0e38f;
    if (tid < 256) v = LAl[tid] + __logf(fmaxf(u_f[tid], 1e-37f));
    float m2 = wred_max(v);
    if (tid < 256 && (tid & 63) == 0) red[tid >> 6] = m2;
    __syncthreads();
    m2 = fmaxf(fmaxf(red[0], red[1]), fmaxf(red[2], red[3]));
    float e = (tid < 256) ? __expf(v - m2) : 0.f;
    float es = wred_add(e);
    __syncthreads();
    if (tid < 256 && (tid & 63) == 0) red[tid >> 6] = es;
    __syncthreads();
    if (tid == 0) per_seq[b] = lm_sh + m2 + __logf(red[0] + red[1] + red[2] + red[3]);
}

// ---- fallback (small ws): read T (f32) directly, exp on the fly.
//      EA holds exp(A), so take logf of it. ----
__global__ __launch_bounds__(256) void k_main_med(const int* xs, const float* T,
                                                  const float* A, const float* LOm,
                                                  const float* LAl, float* per_seq) {
    int b = blockIdx.x, q = threadIdx.x;
    __shared__ int xsh[LDIM];
    __shared__ float red[4];
    __shared__ __align__(16) float u_f[256];
    for (int i = q; i < LDIM; i += 256) xsh[i] = xs[b * LDIM + i];
    float c = LOm[q];
    __syncthreads();
    for (int t = LDIM - 1; t >= 0; --t) {
        int x = xsh[t];
        if (x != 0) {
            float m = wred_max(c);
            if ((q & 63) == 0) red[q >> 6] = m;
            __syncthreads();
            m = fmaxf(fmaxf(red[0], red[1]), fmaxf(red[2], red[3]));
            u_f[q] = __expf(c - m);
            __syncthreads();
            const float* Tp = T + (((size_t)(q << 8) + (size_t)x) << 8);
            float acc = 0.f;
            #pragma unroll 4
            for (int i = 0; i < 32; ++i) {
                float4 ta = *(const float4*)(Tp + (i << 3));
                float4 tb = *(const float4*)(Tp + (i << 3) + 4);
                float4 ua = *(const float4*)(u_f + (i << 3));
                float4 ub = *(const float4*)(u_f + (i << 3) + 4);
                acc = fmaf(__expf(-ta.x), ua.x, acc);
                acc = fmaf(__expf(-ta.y), ua.y, acc);
                acc = fmaf(__expf(-ta.z), ua.z, acc);
                acc = fmaf(__expf(-ta.w), ua.w, acc);
                acc = fmaf(__expf(-tb.x), ub.x, acc);
                acc = fmaf(__expf(-tb.y), ub.y, acc);
                acc = fmaf(__expf(-tb.z), ub.z, acc);
                acc = fmaf(__expf(-tb.w), ub.w, acc);
            }
            acc = fmaxf(acc, 1e-30f);
            c = __logf(A[(x << 8) + q]) + m + __logf(acc);
        }
    }
    float v = LAl[q] + c;
    float m2 = wred_max(v);
    if ((q & 63) == 0) red[q >> 6] = m2;
    __syncthreads();
    m2 = fmaxf(fmaxf(red[0], red[1]), fmaxf(red[2], red[3]));
    float es = wred_add(__expf(v - m2));
    __syncthreads();
    if ((q & 63) == 0) red[q >> 6] = es;
    __syncthreads();
    if (q == 0) per_seq[b] = m2 + __logf(red[0] + red[1] + red[2] + red[3]);
}

__global__ __launch_bounds__(64) void k_final(const float* per_seq, float* out) {
    if (threadIdx.x == 0) {
        float s = 0.f;
        for (int i = 0; i < BDIM; ++i) s += per_seq[i];
        out[0] = s;
    }
}

extern "C" void kernel_launch(void* const* d_in, const int* in_sizes, int n_in,
                              void* d_out, int out_size, void* d_ws, size_t ws_size,
                              hipStream_t stream) {
    const int* xs = nullptr;
    const float *alpha = nullptr, *omega = nullptr, *E = nullptr, *T = nullptr;
    int seen256 = 0;
    for (int i = 0; i < n_in; ++i) {
        int s = in_sizes[i];
        if      (s == 16777216) T  = (const float*)d_in[i];
        else if (s == 65536)    E  = (const float*)d_in[i];
        else if (s == 8192)     xs = (const int*)d_in[i];
        else if (s == 256) { if (seen256++ == 0) alpha = (const float*)d_in[i];
                             else                omega = (const float*)d_in[i]; }
    }

    char* ws = (char*)d_ws;
    float* EA       = (float*)(ws + WS_A);
    float* cE       = (float*)(ws + WS_CE);
    float* LOm      = (float*)(ws + WS_LOM);
    float* LAl      = (float*)(ws + WS_LAL);
    float* per_seq  = (float*)(ws + WS_PS);
    unsigned char* W8 = (unsigned char*)(ws + WS_W);
    int fast = (ws_size >= WS_FAST_BYTES) ? 1 : 0;

    k_erow<<<65, 256, 0, stream>>>(E, omega, alpha, cE, LOm, LAl);
    k_trow<<<4096, 1024, 0, stream>>>(T, E, cE, W8, EA, fast);
    if (fast) k_main_fast<<<BDIM, 1024, 0, stream>>>(xs, W8, EA, LOm, LAl, per_seq);
    else      k_main_med <<<BDIM, 256, 0, stream>>>(xs, T, EA, LOm, LAl, per_seq);
    k_final<<<1, 64, 0, stream>>>(per_seq, (float*)d_out);
}